// Round 3
// baseline (266.717 us; speedup 1.0000x reference)
//
#include <hip/hip_runtime.h>
#include <math.h>

// Problem constants (fixed by setup_inputs)
constexpr int K_ = 4, B_ = 8, T_ = 800, C_ = 80, S_ = 128, Z_ = 32;
constexpr int KB_ = K_ * B_;        // 32
constexpr int TC_ = T_ * C_;        // 64000

#define BIGV   1e8f
#define WARP_V 256.0f

// R12 sheared-stream layout (g=8): Q[u][i] = D[i][u - (i>>3)].
// Lane l owns rows 16l..16l+15 = groups m=0 (cols j0 = u-2l) and m=1 (j1 = j0-1).
// Per step the wave reads Q[u][0..799]: lane reads 64B contiguous, wave 3.2KB.
constexpr int NU_   = 900;            // u = j + (i>>3) <= 799 + 99 = 898
constexpr int SLAB_ = NU_ * 800;      // 720,000 floats per problem (92.16 MB total)

__device__ __forceinline__ float sigmoidf_(float v) {
    return 1.f / (1.f + __expf(-v));
}

// ---------------------------------------------------------------- fill j = -1 ghost cells with BIG
// Lanes l<=11 read Q[2l][16l+8..15] = D[i][-1] once (their first step): must be BIG.
__global__ void fill_edge(float* __restrict__ Dm) {
    int kb = blockIdx.x;
    int t = threadIdx.x;
    if (t < 184) {
        int i = 8 + t;     // i in [8, 191]
        Dm[(size_t)kb * SLAB_ + (size_t)((i >> 3) - 1) * 800 + i] = BIGV;
    }
}

// ---------------------------------------------------------------- banded GEMM -> sheared Q (norms fused)
// grid (5, 13, 32): tiles |ti-tj| <= 2 (written band deviation >= 128 > DP corridor 124).
// Epilogue: LDS shear-transpose -> coalesced 256B u-row stores (edge rows predicated).
__global__ __launch_bounds__(256) void gemm_band(const float* __restrict__ mel_iters,
                                                 const float* __restrict__ mel_targets,
                                                 float* __restrict__ Dm) {
    const int kb = blockIdx.z;
    const int b  = kb & 7;
    const int ti = blockIdx.y;
    const int tj = ti + (int)blockIdx.x - 2;
    if ((unsigned)tj > 12u) return;

    const float* __restrict__ Xb = mel_iters + (size_t)kb * TC_;
    const float* __restrict__ Yb = mel_targets + (size_t)b * TC_;

    __shared__ float smem[4615];            // phase1: xa[16][68] | ya[16][68] | x2s[64] | y2s[64]
    float (*xa)[68] = (float(*)[68])smem;   // phase2: Zt[71][65]
    float (*ya)[68] = (float(*)[68])(smem + 1088);
    float* x2s = smem + 2176;
    float* y2s = smem + 2240;

    const int tid = threadIdx.x;
    const int tx = tid & 15, ty = tid >> 4;
    const int i0 = ti * 64, j0 = tj * 64;
    const int lr = tid >> 4;   // 0..15
    const int lc = tid & 15;   // 0..15  (k within chunk)

    float acc[4][4] = {};
    float nsum = 0.f;          // row-norm partial (tid<64: x2 row tid; tid in [64,128): y2)

    for (int kk = 0; kk < C_; kk += 16) {
        __syncthreads();
        #pragma unroll
        for (int q = 0; q < 4; ++q) {
            int row = lr + q * 16;       // 0..63
            int gi = i0 + row;
            xa[lc][row] = (gi < T_) ? sigmoidf_(Xb[(size_t)gi * C_ + kk + lc]) : 0.f;
            int gj = j0 + row;
            ya[lc][row] = (gj < T_) ? sigmoidf_(Yb[(size_t)gj * C_ + kk + lc]) : 0.f;
        }
        __syncthreads();
        if (tid < 64) {
            #pragma unroll
            for (int k = 0; k < 16; ++k) { float v = xa[k][tid]; nsum += v * v; }
        } else if (tid < 128) {
            #pragma unroll
            for (int k = 0; k < 16; ++k) { float v = ya[k][tid - 64]; nsum += v * v; }
        }
        #pragma unroll
        for (int k = 0; k < 16; ++k) {
            float4 av = *(const float4*)&xa[k][ty * 4];
            float4 bv = *(const float4*)&ya[k][tx * 4];
            acc[0][0] += av.x * bv.x; acc[0][1] += av.x * bv.y; acc[0][2] += av.x * bv.z; acc[0][3] += av.x * bv.w;
            acc[1][0] += av.y * bv.x; acc[1][1] += av.y * bv.y; acc[1][2] += av.y * bv.z; acc[1][3] += av.y * bv.w;
            acc[2][0] += av.z * bv.x; acc[2][1] += av.z * bv.y; acc[2][2] += av.z * bv.z; acc[2][3] += av.z * bv.w;
            acc[3][0] += av.w * bv.x; acc[3][1] += av.w * bv.y; acc[3][2] += av.w * bv.z; acc[3][3] += av.w * bv.w;
        }
    }
    if (tid < 64) x2s[tid] = nsum;
    else if (tid < 128) y2s[tid - 64] = nsum;
    __syncthreads();

    // read norms into regs BEFORE LDS reuse
    float xs2[4], ys2[4];
    #pragma unroll
    for (int r = 0; r < 4; ++r) xs2[r] = x2s[ty * 4 + r];
    #pragma unroll
    for (int c = 0; c < 4; ++c) ys2[c] = y2s[tx * 4 + c];
    __syncthreads();

    // stage into sheared LDS tile: Zt[u_rel][iLoc], u_rel = 4tx + c + (ty>>1)
    float* Zt = smem;                     // [71][65]
    const int sb = ty >> 1;
    #pragma unroll
    for (int r = 0; r < 4; ++r)
        #pragma unroll
        for (int c = 0; c < 4; ++c)
            Zt[(4 * tx + c + sb) * 65 + (4 * ty + r)] = xs2[r] + ys2[c] - 2.f * acc[r][c];
    __syncthreads();

    // coalesced u-row stores: u_global = j0 + 8ti + w, 64 contiguous floats at i0
    const int w0 = tid >> 6;              // wave id 0..3
    const int lane = tid & 63;
    const int iGlob = i0 + lane;
    const int sbl = lane >> 3;            // s(i) - 8ti
    const bool iok = iGlob < T_;
    const size_t ub = (size_t)(j0 + 8 * ti) * 800 + iGlob;
    #pragma unroll
    for (int it = 0; it < 18; ++it) {
        int w = w0 + it * 4;
        if (w > 70) break;
        int jrel = w - sbl;
        if (iok && (unsigned)jrel < 64u && (j0 + jrel) < T_)
            Dm[(size_t)kb * SLAB_ + ub + (size_t)w * 800] = Zt[w * 65 + lane];
    }
}

// ---------------------------------------------------------------- single-wave hard-min DTW, r=16, g=8 shear
// One wave per problem: zero barriers/LDS. Lane l rows 16l..16l+15 in two
// independent 8-chains per step.
//
// R15 ping-pong: stepE reads (sE,wE) writes (sO,wO); stepO the reverse.
// Every cell input is a read of the other buffer -> zero old-value movs
// (R14's `d0 = SA; SA = nA` cost 16 v_mov/step). Cross-step scalars tin/tinW
// alternate parity the same way. Cell = 3 VALU: v_min3, +D, +W.
// Ring shrunk to 4 slots (64 floats) so buffers + state (~115 regs peak)
// fit in arch VGPRs (R13/R14's 96-float ring at VGPR_Count=80 implies the
// compiler parked slots in AGPRs -> v_accvgpr copies, ~32 VALU/step tax).
__device__ __forceinline__ float wave_shr1(float x) {
    int v = __builtin_amdgcn_update_dpp(0, __float_as_int(x), 0x138, 0xf, 0xf, true);
    return __int_as_float(v);
}

#define WAITV(n) asm volatile("s_waitcnt vmcnt(" #n ")" ::: "memory")

__global__ __launch_bounds__(64, 1)
__attribute__((amdgpu_waves_per_eu(1, 1)))
void dtw_wave_kernel(const float* __restrict__ Dm, float* __restrict__ dtwv) {
    const int kb = blockIdx.x;
    const int l  = threadIdx.x;
    const int lc = l < 49 ? l : 49;             // lanes 50-63 mirror lane 49
    const bool is_l0 = (l == 0);
    const float* __restrict__ Dd = Dm + (size_t)kb * SLAB_;

    const int ti_l = lc >> 2;
    const int Jlo = ti_l >= 2 ? 64 * (ti_l - 2) : 0;
    const int Jhi = min(799, 64 * ti_l + 191);
    const int lo_u = (Jlo == 0) ? (2 * lc) : (Jlo + 2 * lc + 1);
    const int hi_u = Jhi + 2 * lc + 1;
    const unsigned lofs = (unsigned)(lc << 4);

    // Ping-pong DP state. s = raw R values, w = s + WARP.
    // E is "latest" before even steps; O before odd steps.
    float sE[16], wE[16], sO[16], wO[16];
    #pragma unroll
    for (int i = 0; i < 16; ++i) { sE[i] = BIGV; wE[i] = BIGV; sO[i] = BIGV; wO[i] = BIGV; }
    float tinE = is_l0 ? 0.f : BIGV;    // tin produced at even steps (init: diag of (0,0))
    float tinO = BIGV;                  // tin produced at odd steps
    float tinWE = BIGV;                 // tinE + W
    float tinWO = BIGV;                 // tinO + W

    auto pref = [&](float4 (&sl)[4], int uu) {
        int uc = min(max(uu, lo_u), hi_u);            // v_med3_i32
        unsigned off = (unsigned)(uc * 800) + lofs;   // elements; fits 32-bit
        const float4* p = (const float4*)(Dd + off);
        sl[0] = p[0];
        sl[1] = p[1];
        sl[2] = p[2];
        sl[3] = p[3];
    };

    // One wavefront step. sIn/wIn = state after previous step; sOut/wOut gets
    // this step's state (previously held t-2 values, consumed only via the two
    // init reads below before being overwritten).
    //   tinRawIn : lane l-1 raw s15 from t-2 (same parity's tin variable, old value)
    //   tinWIn   : lane l-1 s15 + W from t-1 (other parity's tinW)
    #define STEP_PP(sIn, wIn, sOut, wOut, tinRawIO, tinWSame, tinWIn, dq)       \
    {                                                                           \
        float d0 = tinRawIO, uw0 = tinWIn;                                      \
        float d1 = sOut[7], uw1 = wIn[7];        /* old t-2 s7; t-1 w7 */       \
        const float* Dv = (const float*)&dq[0];                                 \
        _Pragma("unroll")                                                       \
        for (int i = 0; i < 8; ++i) {                                           \
            float nA = fminf(fminf(d0, uw0), wIn[i]) + Dv[i];                   \
            float tA = nA + WARP_V;                                             \
            sOut[i] = nA; wOut[i] = tA;                                         \
            d0 = sIn[i]; uw0 = tA;                                              \
            float nB = fminf(fminf(d1, uw1), wIn[i + 8]) + Dv[i + 8];           \
            float tB = nB + WARP_V;                                             \
            sOut[i + 8] = nB; wOut[i + 8] = tB;                                 \
            d1 = sIn[i + 8]; uw1 = tB;                                          \
        }                                                                       \
        float hand = wave_shr1(sOut[15]);                                       \
        tinRawIO = is_l0 ? BIGV : hand;                                         \
        tinWSame = tinRawIO + WARP_V;                                           \
    }
    #define STEP_E(dq) STEP_PP(sE, wE, sO, wO, tinE, tinWE, tinWO, dq)
    #define STEP_O(dq) STEP_PP(sO, wO, sE, wE, tinO, tinWO, tinWE, dq)

    float4 qA[4], qB[4], qC[4], qD[4];
    pref(qA, 0); pref(qB, 1); pref(qC, 2); pref(qD, 3);   // 16 loads in flight

    int u = 0;
    for (int g = 0; g < 224; ++g) {             // steps 0..895
        WAITV(12); STEP_E(qA); pref(qA, u + 4);
        WAITV(12); STEP_O(qB); pref(qB, u + 5);
        WAITV(12); STEP_E(qC); pref(qC, u + 6);
        WAITV(12); STEP_O(qD); pref(qD, u + 7);
        u += 4;
    }
    // u = 896: qA=896(E), qB=897(O), qC=898(E); qD holds clamped junk
    WAITV(12); STEP_E(qA);                      // 896
    WAITV(8);  STEP_O(qB);                      // 897
    WAITV(4);  STEP_E(qC);                      // 898: lane 49 sO[15] = R[800][800]

    if (l == 49) dtwv[kb] = sO[15];
    #undef STEP_E
    #undef STEP_O
    #undef STEP_PP
}

// ---------------------------------------------------------------- finalize (scalars)
__global__ void finalize_kernel(const float* __restrict__ dtwv, const int* __restrict__ mel_lens,
                                const int* __restrict__ src_lens, const float* __restrict__ durations,
                                const float* __restrict__ mus, const float* __restrict__ log_vars,
                                const int* __restrict__ step, float* __restrict__ out) {
    const int lane = threadIdx.x;  // 64 threads, one wave

    float v = (lane < KB_) ? dtwv[lane] : 0.f;
    for (int o = 32; o; o >>= 1) v += __shfl_down(v, o);

    float w = (lane < B_) ? 1.f / (K_ * (float)mel_lens[lane]) : 0.f;
    for (int o = 32; o; o >>= 1) w += __shfl_down(w, o);

    float du = 0.f;
    if (lane < B_) {
        float s = 0.f;
        for (int j = 0; j < S_; ++j) s += durations[lane * S_ + j];
        du = fabsf(s - (float)mel_lens[lane]) / (float)src_lens[lane];
    }
    for (int o = 32; o; o >>= 1) du += __shfl_down(du, o);

    float kl = 0.f;
    for (int j = lane; j < B_ * Z_; j += 64) {
        float muv = mus[j], lv = log_vars[j];
        kl += 1.f + lv - muv * muv - expf(lv);
    }
    for (int o = 32; o; o >>= 1) kl += __shfl_down(kl, o);

    if (lane == 0) {
        float mel_iter_loss = v / (float)B_;
        float mel_loss = mel_iter_loss * (w / (float)B_);
        float dur_loss = 2.0f * du / (float)B_;
        float kl_loss = -0.5f * kl;
        int st = step[0];
        float beta = (st < 2000) ? 0.f : ((st >= 8000) ? 1.f : (float)(st - 2000) / 6000.f);
        out[0] = mel_loss + dur_loss + beta * kl_loss;
        out[1] = mel_loss;
        out[2] = dur_loss;
        out[3] = kl_loss;
        out[4] = beta;
    }
}

// ---------------------------------------------------------------- launch
extern "C" void kernel_launch(void* const* d_in, const int* in_sizes, int n_in,
                              void* d_out, int out_size, void* d_ws, size_t ws_size,
                              hipStream_t stream) {
    const float* mel_iters   = (const float*)d_in[0];
    const float* mel_targets = (const float*)d_in[1];
    const int*   mel_lens    = (const int*)d_in[2];
    const int*   src_lens    = (const int*)d_in[3];
    const float* durations   = (const float*)d_in[4];
    const float* mus         = (const float*)d_in[5];
    const float* log_vars    = (const float*)d_in[6];
    const int*   step        = (const int*)d_in[7];
    float* out = (float*)d_out;

    float* ws   = (float*)d_ws;
    float* Dm   = ws;                              // 32 * 720,000 floats = 92.16 MB
    float* dtwv = Dm + (size_t)KB_ * SLAB_;        //        32

    fill_edge<<<KB_, 192, 0, stream>>>(Dm);

    gemm_band<<<dim3(5, 13, KB_), 256, 0, stream>>>(mel_iters, mel_targets, Dm);

    dtw_wave_kernel<<<KB_, 64, 0, stream>>>(Dm, dtwv);

    finalize_kernel<<<1, 64, 0, stream>>>(dtwv, mel_lens, src_lens, durations, mus, log_vars, step, out);
}

// Round 5
// 217.736 us; speedup vs baseline: 1.2250x; 1.2250x over previous
//
#include <hip/hip_runtime.h>
#include <math.h>
#include <stdint.h>

// Problem constants (fixed by setup_inputs)
constexpr int K_ = 4, B_ = 8, T_ = 800, C_ = 80, S_ = 128, Z_ = 32;
constexpr int KB_ = K_ * B_;        // 32
constexpr int TC_ = T_ * C_;        // 64000

#define BIGV   1e8f
#define WARP_V 256.0f

// R12 sheared-stream layout (g=8): Q[u][i] = D[i][u - (i>>3)].
// Lane l owns rows 16l..16l+15 = groups m=0 (cols j0 = u-2l) and m=1 (j1 = j0-1).
// Per step the wave reads Q[u][0..799]: lane reads 64B contiguous, wave 3.2KB.
constexpr int NU_   = 900;            // u = j + (i>>3) <= 799 + 99 = 898
constexpr int SLAB_ = NU_ * 800;      // 720,000 floats per problem (92.16 MB total)

__device__ __forceinline__ float sigmoidf_(float v) {
    return 1.f / (1.f + __expf(-v));
}

// ---------------------------------------------------------------- fill j = -1 ghost cells with BIG
__global__ void fill_edge(float* __restrict__ Dm) {
    int kb = blockIdx.x;
    int t = threadIdx.x;
    if (t < 184) {
        int i = 8 + t;     // i in [8, 191]
        Dm[(size_t)kb * SLAB_ + (size_t)((i >> 3) - 1) * 800 + i] = BIGV;
    }
}

// ---------------------------------------------------------------- banded GEMM -> sheared Q (norms fused)
__global__ __launch_bounds__(256) void gemm_band(const float* __restrict__ mel_iters,
                                                 const float* __restrict__ mel_targets,
                                                 float* __restrict__ Dm) {
    const int kb = blockIdx.z;
    const int b  = kb & 7;
    const int ti = blockIdx.y;
    const int tj = ti + (int)blockIdx.x - 2;
    if ((unsigned)tj > 12u) return;

    const float* __restrict__ Xb = mel_iters + (size_t)kb * TC_;
    const float* __restrict__ Yb = mel_targets + (size_t)b * TC_;

    __shared__ float smem[4615];            // phase1: xa[16][68] | ya[16][68] | x2s[64] | y2s[64]
    float (*xa)[68] = (float(*)[68])smem;   // phase2: Zt[71][65]
    float (*ya)[68] = (float(*)[68])(smem + 1088);
    float* x2s = smem + 2176;
    float* y2s = smem + 2240;

    const int tid = threadIdx.x;
    const int tx = tid & 15, ty = tid >> 4;
    const int i0 = ti * 64, j0 = tj * 64;
    const int lr = tid >> 4;   // 0..15
    const int lc = tid & 15;   // 0..15  (k within chunk)

    float acc[4][4] = {};
    float nsum = 0.f;

    for (int kk = 0; kk < C_; kk += 16) {
        __syncthreads();
        #pragma unroll
        for (int q = 0; q < 4; ++q) {
            int row = lr + q * 16;       // 0..63
            int gi = i0 + row;
            xa[lc][row] = (gi < T_) ? sigmoidf_(Xb[(size_t)gi * C_ + kk + lc]) : 0.f;
            int gj = j0 + row;
            ya[lc][row] = (gj < T_) ? sigmoidf_(Yb[(size_t)gj * C_ + kk + lc]) : 0.f;
        }
        __syncthreads();
        if (tid < 64) {
            #pragma unroll
            for (int k = 0; k < 16; ++k) { float v = xa[k][tid]; nsum += v * v; }
        } else if (tid < 128) {
            #pragma unroll
            for (int k = 0; k < 16; ++k) { float v = ya[k][tid - 64]; nsum += v * v; }
        }
        #pragma unroll
        for (int k = 0; k < 16; ++k) {
            float4 av = *(const float4*)&xa[k][ty * 4];
            float4 bv = *(const float4*)&ya[k][tx * 4];
            acc[0][0] += av.x * bv.x; acc[0][1] += av.x * bv.y; acc[0][2] += av.x * bv.z; acc[0][3] += av.x * bv.w;
            acc[1][0] += av.y * bv.x; acc[1][1] += av.y * bv.y; acc[1][2] += av.y * bv.z; acc[1][3] += av.y * bv.w;
            acc[2][0] += av.z * bv.x; acc[2][1] += av.z * bv.y; acc[2][2] += av.z * bv.z; acc[2][3] += av.z * bv.w;
            acc[3][0] += av.w * bv.x; acc[3][1] += av.w * bv.y; acc[3][2] += av.w * bv.z; acc[3][3] += av.w * bv.w;
        }
    }
    if (tid < 64) x2s[tid] = nsum;
    else if (tid < 128) y2s[tid - 64] = nsum;
    __syncthreads();

    float xs2[4], ys2[4];
    #pragma unroll
    for (int r = 0; r < 4; ++r) xs2[r] = x2s[ty * 4 + r];
    #pragma unroll
    for (int c = 0; c < 4; ++c) ys2[c] = y2s[tx * 4 + c];
    __syncthreads();

    float* Zt = smem;                     // [71][65]
    const int sb = ty >> 1;
    #pragma unroll
    for (int r = 0; r < 4; ++r)
        #pragma unroll
        for (int c = 0; c < 4; ++c)
            Zt[(4 * tx + c + sb) * 65 + (4 * ty + r)] = xs2[r] + ys2[c] - 2.f * acc[r][c];
    __syncthreads();

    const int w0 = tid >> 6;              // wave id 0..3
    const int lane = tid & 63;
    const int iGlob = i0 + lane;
    const int sbl = lane >> 3;            // s(i) - 8ti
    const bool iok = iGlob < T_;
    const size_t ub = (size_t)(j0 + 8 * ti) * 800 + iGlob;
    #pragma unroll
    for (int it = 0; it < 18; ++it) {
        int w = w0 + it * 4;
        if (w > 70) break;
        int jrel = w - sbl;
        if (iok && (unsigned)jrel < 64u && (j0 + jrel) < T_)
            Dm[(size_t)kb * SLAB_ + ub + (size_t)w * 800] = Zt[w * 65 + lane];
    }
}

// ---------------------------------------------------------------- single-wave hard-min DTW, full inline asm
// R17 = R16 with the macro-expansion fix: `STEP_E SLOT0` never expanded
// (function-like macro not followed by '('); DTW_CALL(M, A) -> M A gets A
// prescan-expanded to the paren list, so the rescan sees STEP_E(...).
// Register map:
//   v42 = BIG  v43,v44 = temps  v45 = tinE  v46 = tinWE  v47 = tinO  v48 = tinWO
//   sE = v50-65  wE = v66-81  sO = v82-97  wO = v98-113
//   ring: 8 slots x 16 floats = v114-v241, 32 loads in flight, wait vmcnt(28)
// Cell: v_min3_f32 (diag, up+W, left+W) ; v_add D ; v_add W  -> 3 VALU, 0 movs.
// Handoff: s_nop 1 ; v_mov_b32_dpp wave_shr:1 ; cndmask(lane0->BIG) ; +W.
// Addressing: s_add (SALU) ; v_med3_i32 clamp ; v_mad_u32_u24 byte-offset ;
// 4x global_load_dwordx4 saddr offset:0/16/32/48.

#define DCELL(dS,dA,dB,dC,dD,dW) \
  "v_min3_f32 v" #dS ", v" #dA ", v" #dB ", v" #dC "\n\t" \
  "v_add_f32 v" #dS ", v" #dS ", v" #dD "\n\t" \
  "v_add_f32 v" #dW ", %[wK], v" #dS "\n\t"

#define STEP_E(q0,q1,q2,q3,q4,q5,q6,q7,q8,q9,q10,q11,q12,q13,q14,q15) \
  DCELL(82, 45, 48, 66, q0, 98)  \
  DCELL(90, 89, 73, 74, q8, 106) \
  DCELL(83, 50, 98, 67, q1, 99)  \
  DCELL(91, 58, 106, 75, q9, 107) \
  DCELL(84, 51, 99, 68, q2, 100) \
  DCELL(92, 59, 107, 76, q10, 108) \
  DCELL(85, 52, 100, 69, q3, 101) \
  DCELL(93, 60, 108, 77, q11, 109) \
  DCELL(86, 53, 101, 70, q4, 102) \
  DCELL(94, 61, 109, 78, q12, 110) \
  DCELL(87, 54, 102, 71, q5, 103) \
  DCELL(95, 62, 110, 79, q13, 111) \
  DCELL(88, 55, 103, 72, q6, 104) \
  DCELL(96, 63, 111, 80, q14, 112) \
  DCELL(89, 56, 104, 73, q7, 105) \
  DCELL(97, 64, 112, 81, q15, 113)

#define STEP_O(q0,q1,q2,q3,q4,q5,q6,q7,q8,q9,q10,q11,q12,q13,q14,q15) \
  DCELL(50, 47, 46, 98, q0, 66)  \
  DCELL(58, 57, 105, 106, q8, 74) \
  DCELL(51, 82, 66, 99, q1, 67)  \
  DCELL(59, 90, 74, 107, q9, 75) \
  DCELL(52, 83, 67, 100, q2, 68) \
  DCELL(60, 91, 75, 108, q10, 76) \
  DCELL(53, 84, 68, 101, q3, 69) \
  DCELL(61, 92, 76, 109, q11, 77) \
  DCELL(54, 85, 69, 102, q4, 70) \
  DCELL(62, 93, 77, 110, q12, 78) \
  DCELL(55, 86, 70, 103, q5, 71) \
  DCELL(63, 94, 78, 111, q13, 79) \
  DCELL(56, 87, 71, 104, q6, 72) \
  DCELL(64, 95, 79, 112, q14, 80) \
  DCELL(57, 88, 72, 105, q7, 73) \
  DCELL(65, 96, 80, 113, q15, 81)

#define HO_E \
  "s_nop 1\n\t" \
  "v_mov_b32_dpp v43, v97 wave_shr:1 row_mask:0xf bank_mask:0xf bound_ctrl:0\n\t" \
  "v_cndmask_b32 v45, v43, v42, %[msk]\n\t" \
  "v_add_f32 v46, %[wK], v45\n\t"

#define HO_O \
  "s_nop 1\n\t" \
  "v_mov_b32_dpp v43, v65 wave_shr:1 row_mask:0xf bank_mask:0xf bound_ctrl:0\n\t" \
  "v_cndmask_b32 v47, v43, v42, %[msk]\n\t" \
  "v_add_f32 v48, %[wK], v47\n\t"

#define PREF(r0,r1,r2,r3,K) \
  "s_add_u32 %[st], %[su], " #K "\n\t" \
  "v_med3_i32 v43, %[st], %[vlo], %[vhi]\n\t" \
  "v_mad_u32_u24 v44, v43, %[c32], %[vl4]\n\t" \
  "global_load_dwordx4 " r0 ", v44, %[bp]\n\t" \
  "global_load_dwordx4 " r1 ", v44, %[bp] offset:16\n\t" \
  "global_load_dwordx4 " r2 ", v44, %[bp] offset:32\n\t" \
  "global_load_dwordx4 " r3 ", v44, %[bp] offset:48\n\t"

#define PREF0(K) PREF("v[114:117]","v[118:121]","v[122:125]","v[126:129]",K)
#define PREF1(K) PREF("v[130:133]","v[134:137]","v[138:141]","v[142:145]",K)
#define PREF2(K) PREF("v[146:149]","v[150:153]","v[154:157]","v[158:161]",K)
#define PREF3(K) PREF("v[162:165]","v[166:169]","v[170:173]","v[174:177]",K)
#define PREF4(K) PREF("v[178:181]","v[182:185]","v[186:189]","v[190:193]",K)
#define PREF5(K) PREF("v[194:197]","v[198:201]","v[202:205]","v[206:209]",K)
#define PREF6(K) PREF("v[210:213]","v[214:217]","v[218:221]","v[222:225]",K)
#define PREF7(K) PREF("v[226:229]","v[230:233]","v[234:237]","v[238:241]",K)

#define SLOT0 (114,115,116,117,118,119,120,121,122,123,124,125,126,127,128,129)
#define SLOT1 (130,131,132,133,134,135,136,137,138,139,140,141,142,143,144,145)
#define SLOT2 (146,147,148,149,150,151,152,153,154,155,156,157,158,159,160,161)
#define SLOT3 (162,163,164,165,166,167,168,169,170,171,172,173,174,175,176,177)
#define SLOT4 (178,179,180,181,182,183,184,185,186,187,188,189,190,191,192,193)
#define SLOT5 (194,195,196,197,198,199,200,201,202,203,204,205,206,207,208,209)
#define SLOT6 (210,211,212,213,214,215,216,217,218,219,220,221,222,223,224,225)
#define SLOT7 (226,227,228,229,230,231,232,233,234,235,236,237,238,239,240,241)

// Indirection so `M` is rescanned adjacent to the prescan-expanded paren list.
#define DTW_CALL(M, A) M A

#define MV(n) "v_mov_b32 v" #n ", v42\n\t"
#define W28 "s_waitcnt vmcnt(28)\n\t"

__global__ __launch_bounds__(64)
void dtw_wave_kernel(const float* __restrict__ Dm, float* __restrict__ dtwv) {
    const int kb = blockIdx.x;
    const int l  = threadIdx.x;
    const int lc = l < 49 ? l : 49;             // lanes 50-63 mirror lane 49
    const float* __restrict__ Dd = Dm + (size_t)kb * SLAB_;

    const int ti_l = lc >> 2;
    const int Jlo = ti_l >= 2 ? 64 * (ti_l - 2) : 0;
    const int Jhi = min(799, 64 * ti_l + 191);
    const int lo_u = (Jlo == 0) ? (2 * lc) : (Jlo + 2 * lc + 1);
    const int hi_u = Jhi + 2 * lc + 1;
    const unsigned lofs4 = (unsigned)(lc << 6);     // byte offset within u-row

    float res;
    unsigned su_d, st_d;

    asm volatile(
        // ---- init constants & state
        "v_mov_b32 v42, %[vbig]\n\t"
        MV(50) MV(51) MV(52) MV(53) MV(54) MV(55) MV(56) MV(57)
        MV(58) MV(59) MV(60) MV(61) MV(62) MV(63) MV(64) MV(65)
        MV(66) MV(67) MV(68) MV(69) MV(70) MV(71) MV(72) MV(73)
        MV(74) MV(75) MV(76) MV(77) MV(78) MV(79) MV(80) MV(81)
        MV(82) MV(83) MV(84) MV(85) MV(86) MV(87) MV(88) MV(89)
        MV(90) MV(91) MV(92) MV(93) MV(94) MV(95) MV(96) MV(97)
        MV(98) MV(99) MV(100) MV(101) MV(102) MV(103) MV(104) MV(105)
        MV(106) MV(107) MV(108) MV(109) MV(110) MV(111) MV(112) MV(113)
        "v_cndmask_b32 v45, v42, 0, %[msk]\n\t"   // tinE: lane0 -> 0, else BIG
        "v_mov_b32 v46, v42\n\t"                  // tinWE (never read before write)
        "v_mov_b32 v47, v42\n\t"                  // tinO
        "v_mov_b32 v48, v42\n\t"                  // tinWO (read at step 0: BIG)
        "s_mov_b32 %[su], 0\n\t"
        // ---- prefill 8 slots (u = 0..7), 32 loads in flight
        PREF0(0) PREF1(1) PREF2(2) PREF3(3) PREF4(4) PREF5(5) PREF6(6) PREF7(7)
        // ---- main loop: 111 iters x 8 steps = steps 0..887
        "1:\n\t"
        W28 DTW_CALL(STEP_E, SLOT0) HO_E PREF0(8)
        W28 DTW_CALL(STEP_O, SLOT1) HO_O PREF1(9)
        W28 DTW_CALL(STEP_E, SLOT2) HO_E PREF2(10)
        W28 DTW_CALL(STEP_O, SLOT3) HO_O PREF3(11)
        W28 DTW_CALL(STEP_E, SLOT4) HO_E PREF4(12)
        W28 DTW_CALL(STEP_O, SLOT5) HO_O PREF5(13)
        W28 DTW_CALL(STEP_E, SLOT6) HO_E PREF6(14)
        W28 DTW_CALL(STEP_O, SLOT7) HO_O PREF7(15)
        "s_add_u32 %[su], %[su], 8\n\t"
        "s_cmp_lg_u32 %[su], 888\n\t"
        "s_cbranch_scc1 1b\n\t"
        // ---- tail: steps 888..898 (su = 888)
        W28 DTW_CALL(STEP_E, SLOT0) HO_E PREF0(8)            // 888, refill 896
        W28 DTW_CALL(STEP_O, SLOT1) HO_O PREF1(9)            // 889, refill 897
        W28 DTW_CALL(STEP_E, SLOT2) HO_E PREF2(10)           // 890, refill 898
        W28 DTW_CALL(STEP_O, SLOT3) HO_O                     // 891
        "s_waitcnt vmcnt(24)\n\t" DTW_CALL(STEP_E, SLOT4) HO_E   // 892
        "s_waitcnt vmcnt(20)\n\t" DTW_CALL(STEP_O, SLOT5) HO_O   // 893
        "s_waitcnt vmcnt(16)\n\t" DTW_CALL(STEP_E, SLOT6) HO_E   // 894
        "s_waitcnt vmcnt(12)\n\t" DTW_CALL(STEP_O, SLOT7) HO_O   // 895
        "s_waitcnt vmcnt(8)\n\t"  DTW_CALL(STEP_E, SLOT0) HO_E   // 896
        "s_waitcnt vmcnt(4)\n\t"  DTW_CALL(STEP_O, SLOT1) HO_O   // 897
        "s_waitcnt vmcnt(0)\n\t"  DTW_CALL(STEP_E, SLOT2)        // 898
        "v_mov_b32 %[res], v97\n\t"
        : [res] "=v"(res), [su] "=&s"(su_d), [st] "=&s"(st_d)
        : [vlo] "v"(lo_u), [vhi] "v"(hi_u), [vl4] "v"(lofs4),
          [vbig] "v"(BIGV), [wK] "s"(WARP_V), [c32] "s"(3200u),
          [msk] "s"(1ull), [bp] "s"((const void*)Dd)
        : "memory", "scc",
          "v42","v43","v44","v45","v46","v47","v48","v49",
          "v50","v51","v52","v53","v54","v55","v56","v57","v58","v59",
          "v60","v61","v62","v63","v64","v65","v66","v67","v68","v69",
          "v70","v71","v72","v73","v74","v75","v76","v77","v78","v79",
          "v80","v81","v82","v83","v84","v85","v86","v87","v88","v89",
          "v90","v91","v92","v93","v94","v95","v96","v97","v98","v99",
          "v100","v101","v102","v103","v104","v105","v106","v107","v108","v109",
          "v110","v111","v112","v113","v114","v115","v116","v117","v118","v119",
          "v120","v121","v122","v123","v124","v125","v126","v127","v128","v129",
          "v130","v131","v132","v133","v134","v135","v136","v137","v138","v139",
          "v140","v141","v142","v143","v144","v145","v146","v147","v148","v149",
          "v150","v151","v152","v153","v154","v155","v156","v157","v158","v159",
          "v160","v161","v162","v163","v164","v165","v166","v167","v168","v169",
          "v170","v171","v172","v173","v174","v175","v176","v177","v178","v179",
          "v180","v181","v182","v183","v184","v185","v186","v187","v188","v189",
          "v190","v191","v192","v193","v194","v195","v196","v197","v198","v199",
          "v200","v201","v202","v203","v204","v205","v206","v207","v208","v209",
          "v210","v211","v212","v213","v214","v215","v216","v217","v218","v219",
          "v220","v221","v222","v223","v224","v225","v226","v227","v228","v229",
          "v230","v231","v232","v233","v234","v235","v236","v237","v238","v239",
          "v240","v241"
    );

    if (l == 49) dtwv[kb] = res;
}

// ---------------------------------------------------------------- finalize (scalars)
__global__ void finalize_kernel(const float* __restrict__ dtwv, const int* __restrict__ mel_lens,
                                const int* __restrict__ src_lens, const float* __restrict__ durations,
                                const float* __restrict__ mus, const float* __restrict__ log_vars,
                                const int* __restrict__ step, float* __restrict__ out) {
    const int lane = threadIdx.x;  // 64 threads, one wave

    float v = (lane < KB_) ? dtwv[lane] : 0.f;
    for (int o = 32; o; o >>= 1) v += __shfl_down(v, o);

    float w = (lane < B_) ? 1.f / (K_ * (float)mel_lens[lane]) : 0.f;
    for (int o = 32; o; o >>= 1) w += __shfl_down(w, o);

    float du = 0.f;
    if (lane < B_) {
        float s = 0.f;
        for (int j = 0; j < S_; ++j) s += durations[lane * S_ + j];
        du = fabsf(s - (float)mel_lens[lane]) / (float)src_lens[lane];
    }
    for (int o = 32; o; o >>= 1) du += __shfl_down(du, o);

    float kl = 0.f;
    for (int j = lane; j < B_ * Z_; j += 64) {
        float muv = mus[j], lv = log_vars[j];
        kl += 1.f + lv - muv * muv - expf(lv);
    }
    for (int o = 32; o; o >>= 1) kl += __shfl_down(kl, o);

    if (lane == 0) {
        float mel_iter_loss = v / (float)B_;
        float mel_loss = mel_iter_loss * (w / (float)B_);
        float dur_loss = 2.0f * du / (float)B_;
        float kl_loss = -0.5f * kl;
        int st = step[0];
        float beta = (st < 2000) ? 0.f : ((st >= 8000) ? 1.f : (float)(st - 2000) / 6000.f);
        out[0] = mel_loss + dur_loss + beta * kl_loss;
        out[1] = mel_loss;
        out[2] = dur_loss;
        out[3] = kl_loss;
        out[4] = beta;
    }
}

// ---------------------------------------------------------------- launch
extern "C" void kernel_launch(void* const* d_in, const int* in_sizes, int n_in,
                              void* d_out, int out_size, void* d_ws, size_t ws_size,
                              hipStream_t stream) {
    const float* mel_iters   = (const float*)d_in[0];
    const float* mel_targets = (const float*)d_in[1];
    const int*   mel_lens    = (const int*)d_in[2];
    const int*   src_lens    = (const int*)d_in[3];
    const float* durations   = (const float*)d_in[4];
    const float* mus         = (const float*)d_in[5];
    const float* log_vars    = (const float*)d_in[6];
    const int*   step        = (const int*)d_in[7];
    float* out = (float*)d_out;

    float* ws   = (float*)d_ws;
    float* Dm   = ws;                              // 32 * 720,000 floats = 92.16 MB
    float* dtwv = Dm + (size_t)KB_ * SLAB_;        //        32

    fill_edge<<<KB_, 192, 0, stream>>>(Dm);

    gemm_band<<<dim3(5, 13, KB_), 256, 0, stream>>>(mel_iters, mel_targets, Dm);

    dtw_wave_kernel<<<KB_, 64, 0, stream>>>(Dm, dtwv);

    finalize_kernel<<<1, 64, 0, stream>>>(dtwv, mel_lens, src_lens, durations, mus, log_vars, step, out);
}

// Round 6
// 217.196 us; speedup vs baseline: 1.2280x; 1.0025x over previous
//
#include <hip/hip_runtime.h>
#include <math.h>
#include <stdint.h>

// Problem constants (fixed by setup_inputs)
constexpr int K_ = 4, B_ = 8, T_ = 800, C_ = 80, S_ = 128, Z_ = 32;
constexpr int KB_ = K_ * B_;        // 32
constexpr int TC_ = T_ * C_;        // 64000

#define BIGV   1e8f
#define WARP_V 256.0f

// R12 sheared-stream layout (g=8): Q[u][i] = D[i][u - (i>>3)].
// Lane l owns rows 16l..16l+15 = groups m=0 (cols j0 = u-2l) and m=1 (j1 = j0-1).
// Per step the wave reads Q[u][0..799]: lane reads 64B contiguous, wave 3.2KB.
constexpr int NU_   = 900;            // u = j + (i>>3) <= 799 + 99 = 898
constexpr int SLAB_ = NU_ * 800;      // 720,000 floats per problem (92.16 MB total)

__device__ __forceinline__ float sigmoidf_(float v) {
    return 1.f / (1.f + __expf(-v));
}

// ---------------------------------------------------------------- fill j = -1 ghost cells with BIG
__global__ void fill_edge(float* __restrict__ Dm) {
    int kb = blockIdx.x;
    int t = threadIdx.x;
    if (t < 184) {
        int i = 8 + t;     // i in [8, 191]
        Dm[(size_t)kb * SLAB_ + (size_t)((i >> 3) - 1) * 800 + i] = BIGV;
    }
}

// ---------------------------------------------------------------- banded GEMM -> sheared Q (norms fused)
__global__ __launch_bounds__(256) void gemm_band(const float* __restrict__ mel_iters,
                                                 const float* __restrict__ mel_targets,
                                                 float* __restrict__ Dm) {
    const int kb = blockIdx.z;
    const int b  = kb & 7;
    const int ti = blockIdx.y;
    const int tj = ti + (int)blockIdx.x - 2;
    if ((unsigned)tj > 12u) return;

    const float* __restrict__ Xb = mel_iters + (size_t)kb * TC_;
    const float* __restrict__ Yb = mel_targets + (size_t)b * TC_;

    __shared__ float smem[4615];            // phase1: xa[16][68] | ya[16][68] | x2s[64] | y2s[64]
    float (*xa)[68] = (float(*)[68])smem;   // phase2: Zt[71][65]
    float (*ya)[68] = (float(*)[68])(smem + 1088);
    float* x2s = smem + 2176;
    float* y2s = smem + 2240;

    const int tid = threadIdx.x;
    const int tx = tid & 15, ty = tid >> 4;
    const int i0 = ti * 64, j0 = tj * 64;
    const int lr = tid >> 4;   // 0..15
    const int lc = tid & 15;   // 0..15  (k within chunk)

    float acc[4][4] = {};
    float nsum = 0.f;

    for (int kk = 0; kk < C_; kk += 16) {
        __syncthreads();
        #pragma unroll
        for (int q = 0; q < 4; ++q) {
            int row = lr + q * 16;       // 0..63
            int gi = i0 + row;
            xa[lc][row] = (gi < T_) ? sigmoidf_(Xb[(size_t)gi * C_ + kk + lc]) : 0.f;
            int gj = j0 + row;
            ya[lc][row] = (gj < T_) ? sigmoidf_(Yb[(size_t)gj * C_ + kk + lc]) : 0.f;
        }
        __syncthreads();
        if (tid < 64) {
            #pragma unroll
            for (int k = 0; k < 16; ++k) { float v = xa[k][tid]; nsum += v * v; }
        } else if (tid < 128) {
            #pragma unroll
            for (int k = 0; k < 16; ++k) { float v = ya[k][tid - 64]; nsum += v * v; }
        }
        #pragma unroll
        for (int k = 0; k < 16; ++k) {
            float4 av = *(const float4*)&xa[k][ty * 4];
            float4 bv = *(const float4*)&ya[k][tx * 4];
            acc[0][0] += av.x * bv.x; acc[0][1] += av.x * bv.y; acc[0][2] += av.x * bv.z; acc[0][3] += av.x * bv.w;
            acc[1][0] += av.y * bv.x; acc[1][1] += av.y * bv.y; acc[1][2] += av.y * bv.z; acc[1][3] += av.y * bv.w;
            acc[2][0] += av.z * bv.x; acc[2][1] += av.z * bv.y; acc[2][2] += av.z * bv.z; acc[2][3] += av.z * bv.w;
            acc[3][0] += av.w * bv.x; acc[3][1] += av.w * bv.y; acc[3][2] += av.w * bv.z; acc[3][3] += av.w * bv.w;
        }
    }
    if (tid < 64) x2s[tid] = nsum;
    else if (tid < 128) y2s[tid - 64] = nsum;
    __syncthreads();

    float xs2[4], ys2[4];
    #pragma unroll
    for (int r = 0; r < 4; ++r) xs2[r] = x2s[ty * 4 + r];
    #pragma unroll
    for (int c = 0; c < 4; ++c) ys2[c] = y2s[tx * 4 + c];
    __syncthreads();

    float* Zt = smem;                     // [71][65]
    const int sb = ty >> 1;
    #pragma unroll
    for (int r = 0; r < 4; ++r)
        #pragma unroll
        for (int c = 0; c < 4; ++c)
            Zt[(4 * tx + c + sb) * 65 + (4 * ty + r)] = xs2[r] + ys2[c] - 2.f * acc[r][c];
    __syncthreads();

    const int w0 = tid >> 6;              // wave id 0..3
    const int lane = tid & 63;
    const int iGlob = i0 + lane;
    const int sbl = lane >> 3;            // s(i) - 8ti
    const bool iok = iGlob < T_;
    const size_t ub = (size_t)(j0 + 8 * ti) * 800 + iGlob;
    #pragma unroll
    for (int it = 0; it < 18; ++it) {
        int w = w0 + it * 4;
        if (w > 70) break;
        int jrel = w - sbl;
        if (iok && (unsigned)jrel < 64u && (j0 + jrel) < T_)
            Dm[(size_t)kb * SLAB_ + ub + (size_t)w * 800] = Zt[w * 65 + lane];
    }
}

// ---------------------------------------------------------------- single-wave hard-min DTW, full inline asm
// R18 = R17 with instruction-level dual-chain interleave. R17 emitted each
// cell's 3 serially-dependent ops consecutively (min3->addD->addW), so the
// in-order wave ran them at full 4-cy latency each (VALUBusy showed ~196
// busy-cy/step = 4cy x 48) and the second independent chain couldn't fill
// the bubbles. DCELL2 emits min3(A),min3(B),addD(A),addD(B),addW(A),addW(B):
// dependent ops are now 2 insts (~4cy) apart -> issue-rate bound (~2cy/inst).
// Register map (unchanged):
//   v42 = BIG  v43,v44 = temps  v45 = tinE  v46 = tinWE  v47 = tinO  v48 = tinWO
//   sE = v50-65  wE = v66-81  sO = v82-97  wO = v98-113
//   ring: 8 slots x 16 floats = v114-v241, 32 loads in flight, wait vmcnt(28)

#define DCELL2(aS,aA,aB,aC,aD,aW, bS,bA,bB,bC,bD,bW) \
  "v_min3_f32 v" #aS ", v" #aA ", v" #aB ", v" #aC "\n\t" \
  "v_min3_f32 v" #bS ", v" #bA ", v" #bB ", v" #bC "\n\t" \
  "v_add_f32 v" #aS ", v" #aS ", v" #aD "\n\t" \
  "v_add_f32 v" #bS ", v" #bS ", v" #bD "\n\t" \
  "v_add_f32 v" #aW ", %[wK], v" #aS "\n\t" \
  "v_add_f32 v" #bW ", %[wK], v" #bS "\n\t"

#define STEP_E(q0,q1,q2,q3,q4,q5,q6,q7,q8,q9,q10,q11,q12,q13,q14,q15) \
  DCELL2(82, 45, 48, 66, q0, 98,    90, 89, 73, 74, q8, 106) \
  DCELL2(83, 50, 98, 67, q1, 99,    91, 58, 106, 75, q9, 107) \
  DCELL2(84, 51, 99, 68, q2, 100,   92, 59, 107, 76, q10, 108) \
  DCELL2(85, 52, 100, 69, q3, 101,  93, 60, 108, 77, q11, 109) \
  DCELL2(86, 53, 101, 70, q4, 102,  94, 61, 109, 78, q12, 110) \
  DCELL2(87, 54, 102, 71, q5, 103,  95, 62, 110, 79, q13, 111) \
  DCELL2(88, 55, 103, 72, q6, 104,  96, 63, 111, 80, q14, 112) \
  DCELL2(89, 56, 104, 73, q7, 105,  97, 64, 112, 81, q15, 113)

#define STEP_O(q0,q1,q2,q3,q4,q5,q6,q7,q8,q9,q10,q11,q12,q13,q14,q15) \
  DCELL2(50, 47, 46, 98, q0, 66,    58, 57, 105, 106, q8, 74) \
  DCELL2(51, 82, 66, 99, q1, 67,    59, 90, 74, 107, q9, 75) \
  DCELL2(52, 83, 67, 100, q2, 68,   60, 91, 75, 108, q10, 76) \
  DCELL2(53, 84, 68, 101, q3, 69,   61, 92, 76, 109, q11, 77) \
  DCELL2(54, 85, 69, 102, q4, 70,   62, 93, 77, 110, q12, 78) \
  DCELL2(55, 86, 70, 103, q5, 71,   63, 94, 78, 111, q13, 79) \
  DCELL2(56, 87, 71, 104, q6, 72,   64, 95, 79, 112, q14, 80) \
  DCELL2(57, 88, 72, 105, q7, 73,   65, 96, 80, 113, q15, 81)

#define HO_E \
  "s_nop 1\n\t" \
  "v_mov_b32_dpp v43, v97 wave_shr:1 row_mask:0xf bank_mask:0xf bound_ctrl:0\n\t" \
  "v_cndmask_b32 v45, v43, v42, %[msk]\n\t" \
  "v_add_f32 v46, %[wK], v45\n\t"

#define HO_O \
  "s_nop 1\n\t" \
  "v_mov_b32_dpp v43, v65 wave_shr:1 row_mask:0xf bank_mask:0xf bound_ctrl:0\n\t" \
  "v_cndmask_b32 v47, v43, v42, %[msk]\n\t" \
  "v_add_f32 v48, %[wK], v47\n\t"

#define PREF(r0,r1,r2,r3,K) \
  "s_add_u32 %[st], %[su], " #K "\n\t" \
  "v_med3_i32 v43, %[st], %[vlo], %[vhi]\n\t" \
  "v_mad_u32_u24 v44, v43, %[c32], %[vl4]\n\t" \
  "global_load_dwordx4 " r0 ", v44, %[bp]\n\t" \
  "global_load_dwordx4 " r1 ", v44, %[bp] offset:16\n\t" \
  "global_load_dwordx4 " r2 ", v44, %[bp] offset:32\n\t" \
  "global_load_dwordx4 " r3 ", v44, %[bp] offset:48\n\t"

#define PREF0(K) PREF("v[114:117]","v[118:121]","v[122:125]","v[126:129]",K)
#define PREF1(K) PREF("v[130:133]","v[134:137]","v[138:141]","v[142:145]",K)
#define PREF2(K) PREF("v[146:149]","v[150:153]","v[154:157]","v[158:161]",K)
#define PREF3(K) PREF("v[162:165]","v[166:169]","v[170:173]","v[174:177]",K)
#define PREF4(K) PREF("v[178:181]","v[182:185]","v[186:189]","v[190:193]",K)
#define PREF5(K) PREF("v[194:197]","v[198:201]","v[202:205]","v[206:209]",K)
#define PREF6(K) PREF("v[210:213]","v[214:217]","v[218:221]","v[222:225]",K)
#define PREF7(K) PREF("v[226:229]","v[230:233]","v[234:237]","v[238:241]",K)

#define SLOT0 (114,115,116,117,118,119,120,121,122,123,124,125,126,127,128,129)
#define SLOT1 (130,131,132,133,134,135,136,137,138,139,140,141,142,143,144,145)
#define SLOT2 (146,147,148,149,150,151,152,153,154,155,156,157,158,159,160,161)
#define SLOT3 (162,163,164,165,166,167,168,169,170,171,172,173,174,175,176,177)
#define SLOT4 (178,179,180,181,182,183,184,185,186,187,188,189,190,191,192,193)
#define SLOT5 (194,195,196,197,198,199,200,201,202,203,204,205,206,207,208,209)
#define SLOT6 (210,211,212,213,214,215,216,217,218,219,220,221,222,223,224,225)
#define SLOT7 (226,227,228,229,230,231,232,233,234,235,236,237,238,239,240,241)

// Indirection so `M` is rescanned adjacent to the prescan-expanded paren list.
#define DTW_CALL(M, A) M A

#define MV(n) "v_mov_b32 v" #n ", v42\n\t"
#define W28 "s_waitcnt vmcnt(28)\n\t"

__global__ __launch_bounds__(64)
void dtw_wave_kernel(const float* __restrict__ Dm, float* __restrict__ dtwv) {
    const int kb = blockIdx.x;
    const int l  = threadIdx.x;
    const int lc = l < 49 ? l : 49;             // lanes 50-63 mirror lane 49
    const float* __restrict__ Dd = Dm + (size_t)kb * SLAB_;

    const int ti_l = lc >> 2;
    const int Jlo = ti_l >= 2 ? 64 * (ti_l - 2) : 0;
    const int Jhi = min(799, 64 * ti_l + 191);
    const int lo_u = (Jlo == 0) ? (2 * lc) : (Jlo + 2 * lc + 1);
    const int hi_u = Jhi + 2 * lc + 1;
    const unsigned lofs4 = (unsigned)(lc << 6);     // byte offset within u-row

    float res;
    unsigned su_d, st_d;

    asm volatile(
        // ---- init constants & state
        "v_mov_b32 v42, %[vbig]\n\t"
        MV(50) MV(51) MV(52) MV(53) MV(54) MV(55) MV(56) MV(57)
        MV(58) MV(59) MV(60) MV(61) MV(62) MV(63) MV(64) MV(65)
        MV(66) MV(67) MV(68) MV(69) MV(70) MV(71) MV(72) MV(73)
        MV(74) MV(75) MV(76) MV(77) MV(78) MV(79) MV(80) MV(81)
        MV(82) MV(83) MV(84) MV(85) MV(86) MV(87) MV(88) MV(89)
        MV(90) MV(91) MV(92) MV(93) MV(94) MV(95) MV(96) MV(97)
        MV(98) MV(99) MV(100) MV(101) MV(102) MV(103) MV(104) MV(105)
        MV(106) MV(107) MV(108) MV(109) MV(110) MV(111) MV(112) MV(113)
        "v_cndmask_b32 v45, v42, 0, %[msk]\n\t"   // tinE: lane0 -> 0, else BIG
        "v_mov_b32 v46, v42\n\t"                  // tinWE (never read before write)
        "v_mov_b32 v47, v42\n\t"                  // tinO
        "v_mov_b32 v48, v42\n\t"                  // tinWO (read at step 0: BIG)
        "s_mov_b32 %[su], 0\n\t"
        // ---- prefill 8 slots (u = 0..7), 32 loads in flight
        PREF0(0) PREF1(1) PREF2(2) PREF3(3) PREF4(4) PREF5(5) PREF6(6) PREF7(7)
        // ---- main loop: 111 iters x 8 steps = steps 0..887
        "1:\n\t"
        W28 DTW_CALL(STEP_E, SLOT0) HO_E PREF0(8)
        W28 DTW_CALL(STEP_O, SLOT1) HO_O PREF1(9)
        W28 DTW_CALL(STEP_E, SLOT2) HO_E PREF2(10)
        W28 DTW_CALL(STEP_O, SLOT3) HO_O PREF3(11)
        W28 DTW_CALL(STEP_E, SLOT4) HO_E PREF4(12)
        W28 DTW_CALL(STEP_O, SLOT5) HO_O PREF5(13)
        W28 DTW_CALL(STEP_E, SLOT6) HO_E PREF6(14)
        W28 DTW_CALL(STEP_O, SLOT7) HO_O PREF7(15)
        "s_add_u32 %[su], %[su], 8\n\t"
        "s_cmp_lg_u32 %[su], 888\n\t"
        "s_cbranch_scc1 1b\n\t"
        // ---- tail: steps 888..898 (su = 888)
        W28 DTW_CALL(STEP_E, SLOT0) HO_E PREF0(8)            // 888, refill 896
        W28 DTW_CALL(STEP_O, SLOT1) HO_O PREF1(9)            // 889, refill 897
        W28 DTW_CALL(STEP_E, SLOT2) HO_E PREF2(10)           // 890, refill 898
        W28 DTW_CALL(STEP_O, SLOT3) HO_O                     // 891
        "s_waitcnt vmcnt(24)\n\t" DTW_CALL(STEP_E, SLOT4) HO_E   // 892
        "s_waitcnt vmcnt(20)\n\t" DTW_CALL(STEP_O, SLOT5) HO_O   // 893
        "s_waitcnt vmcnt(16)\n\t" DTW_CALL(STEP_E, SLOT6) HO_E   // 894
        "s_waitcnt vmcnt(12)\n\t" DTW_CALL(STEP_O, SLOT7) HO_O   // 895
        "s_waitcnt vmcnt(8)\n\t"  DTW_CALL(STEP_E, SLOT0) HO_E   // 896
        "s_waitcnt vmcnt(4)\n\t"  DTW_CALL(STEP_O, SLOT1) HO_O   // 897
        "s_waitcnt vmcnt(0)\n\t"  DTW_CALL(STEP_E, SLOT2)        // 898
        "v_mov_b32 %[res], v97\n\t"
        : [res] "=v"(res), [su] "=&s"(su_d), [st] "=&s"(st_d)
        : [vlo] "v"(lo_u), [vhi] "v"(hi_u), [vl4] "v"(lofs4),
          [vbig] "v"(BIGV), [wK] "s"(WARP_V), [c32] "s"(3200u),
          [msk] "s"(1ull), [bp] "s"((const void*)Dd)
        : "memory", "scc",
          "v42","v43","v44","v45","v46","v47","v48","v49",
          "v50","v51","v52","v53","v54","v55","v56","v57","v58","v59",
          "v60","v61","v62","v63","v64","v65","v66","v67","v68","v69",
          "v70","v71","v72","v73","v74","v75","v76","v77","v78","v79",
          "v80","v81","v82","v83","v84","v85","v86","v87","v88","v89",
          "v90","v91","v92","v93","v94","v95","v96","v97","v98","v99",
          "v100","v101","v102","v103","v104","v105","v106","v107","v108","v109",
          "v110","v111","v112","v113","v114","v115","v116","v117","v118","v119",
          "v120","v121","v122","v123","v124","v125","v126","v127","v128","v129",
          "v130","v131","v132","v133","v134","v135","v136","v137","v138","v139",
          "v140","v141","v142","v143","v144","v145","v146","v147","v148","v149",
          "v150","v151","v152","v153","v154","v155","v156","v157","v158","v159",
          "v160","v161","v162","v163","v164","v165","v166","v167","v168","v169",
          "v170","v171","v172","v173","v174","v175","v176","v177","v178","v179",
          "v180","v181","v182","v183","v184","v185","v186","v187","v188","v189",
          "v190","v191","v192","v193","v194","v195","v196","v197","v198","v199",
          "v200","v201","v202","v203","v204","v205","v206","v207","v208","v209",
          "v210","v211","v212","v213","v214","v215","v216","v217","v218","v219",
          "v220","v221","v222","v223","v224","v225","v226","v227","v228","v229",
          "v230","v231","v232","v233","v234","v235","v236","v237","v238","v239",
          "v240","v241"
    );

    if (l == 49) dtwv[kb] = res;
}

// ---------------------------------------------------------------- finalize (scalars)
__global__ void finalize_kernel(const float* __restrict__ dtwv, const int* __restrict__ mel_lens,
                                const int* __restrict__ src_lens, const float* __restrict__ durations,
                                const float* __restrict__ mus, const float* __restrict__ log_vars,
                                const int* __restrict__ step, float* __restrict__ out) {
    const int lane = threadIdx.x;  // 64 threads, one wave

    float v = (lane < KB_) ? dtwv[lane] : 0.f;
    for (int o = 32; o; o >>= 1) v += __shfl_down(v, o);

    float w = (lane < B_) ? 1.f / (K_ * (float)mel_lens[lane]) : 0.f;
    for (int o = 32; o; o >>= 1) w += __shfl_down(w, o);

    float du = 0.f;
    if (lane < B_) {
        float s = 0.f;
        for (int j = 0; j < S_; ++j) s += durations[lane * S_ + j];
        du = fabsf(s - (float)mel_lens[lane]) / (float)src_lens[lane];
    }
    for (int o = 32; o; o >>= 1) du += __shfl_down(du, o);

    float kl = 0.f;
    for (int j = lane; j < B_ * Z_; j += 64) {
        float muv = mus[j], lv = log_vars[j];
        kl += 1.f + lv - muv * muv - expf(lv);
    }
    for (int o = 32; o; o >>= 1) kl += __shfl_down(kl, o);

    if (lane == 0) {
        float mel_iter_loss = v / (float)B_;
        float mel_loss = mel_iter_loss * (w / (float)B_);
        float dur_loss = 2.0f * du / (float)B_;
        float kl_loss = -0.5f * kl;
        int st = step[0];
        float beta = (st < 2000) ? 0.f : ((st >= 8000) ? 1.f : (float)(st - 2000) / 6000.f);
        out[0] = mel_loss + dur_loss + beta * kl_loss;
        out[1] = mel_loss;
        out[2] = dur_loss;
        out[3] = kl_loss;
        out[4] = beta;
    }
}

// ---------------------------------------------------------------- launch
extern "C" void kernel_launch(void* const* d_in, const int* in_sizes, int n_in,
                              void* d_out, int out_size, void* d_ws, size_t ws_size,
                              hipStream_t stream) {
    const float* mel_iters   = (const float*)d_in[0];
    const float* mel_targets = (const float*)d_in[1];
    const int*   mel_lens    = (const int*)d_in[2];
    const int*   src_lens    = (const int*)d_in[3];
    const float* durations   = (const float*)d_in[4];
    const float* mus         = (const float*)d_in[5];
    const float* log_vars    = (const float*)d_in[6];
    const int*   step        = (const int*)d_in[7];
    float* out = (float*)d_out;

    float* ws   = (float*)d_ws;
    float* Dm   = ws;                              // 32 * 720,000 floats = 92.16 MB
    float* dtwv = Dm + (size_t)KB_ * SLAB_;        //        32

    fill_edge<<<KB_, 192, 0, stream>>>(Dm);

    gemm_band<<<dim3(5, 13, KB_), 256, 0, stream>>>(mel_iters, mel_targets, Dm);

    dtw_wave_kernel<<<KB_, 64, 0, stream>>>(Dm, dtwv);

    finalize_kernel<<<1, 64, 0, stream>>>(dtwv, mel_lens, src_lens, durations, mus, log_vars, step, out);
}

// Round 7
// 216.177 us; speedup vs baseline: 1.2338x; 1.0047x over previous
//
#include <hip/hip_runtime.h>
#include <math.h>
#include <stdint.h>

// Problem constants (fixed by setup_inputs)
constexpr int K_ = 4, B_ = 8, T_ = 800, C_ = 80, S_ = 128, Z_ = 32;
constexpr int KB_ = K_ * B_;        // 32
constexpr int TC_ = T_ * C_;        // 64000

#define BIGV   1e8f
#define WARP_V 256.0f

// R12 sheared-stream layout (g=8): Q[u][i] = D'[i][u - (i>>3)], where
// R19: Q stores D' = D + WARP (DW-form DP: m = min3(s_dg, m_up, m_lf) + D',
// raw s = m - W recovered off-chain). Chain dep/cell: 2 ops instead of 3.
constexpr int NU_   = 900;            // u = j + (i>>3) <= 799 + 99 = 898
constexpr int SLAB_ = NU_ * 800;      // 720,000 floats per problem (92.16 MB total)

__device__ __forceinline__ float sigmoidf_(float v) {
    return 1.f / (1.f + __expf(-v));
}

// ---------------------------------------------------------------- fill j = -1 ghost cells with BIG
__global__ void fill_edge(float* __restrict__ Dm) {
    int kb = blockIdx.x;
    int t = threadIdx.x;
    if (t < 184) {
        int i = 8 + t;     // i in [8, 191]
        Dm[(size_t)kb * SLAB_ + (size_t)((i >> 3) - 1) * 800 + i] = BIGV;
    }
}

// ---------------------------------------------------------------- banded GEMM -> sheared Q (norms fused)
// R19: epilogue writes D + WARP (DW-form for the DTW kernel).
__global__ __launch_bounds__(256) void gemm_band(const float* __restrict__ mel_iters,
                                                 const float* __restrict__ mel_targets,
                                                 float* __restrict__ Dm) {
    const int kb = blockIdx.z;
    const int b  = kb & 7;
    const int ti = blockIdx.y;
    const int tj = ti + (int)blockIdx.x - 2;
    if ((unsigned)tj > 12u) return;

    const float* __restrict__ Xb = mel_iters + (size_t)kb * TC_;
    const float* __restrict__ Yb = mel_targets + (size_t)b * TC_;

    __shared__ float smem[4615];            // phase1: xa[16][68] | ya[16][68] | x2s[64] | y2s[64]
    float (*xa)[68] = (float(*)[68])smem;   // phase2: Zt[71][65]
    float (*ya)[68] = (float(*)[68])(smem + 1088);
    float* x2s = smem + 2176;
    float* y2s = smem + 2240;

    const int tid = threadIdx.x;
    const int tx = tid & 15, ty = tid >> 4;
    const int i0 = ti * 64, j0 = tj * 64;
    const int lr = tid >> 4;   // 0..15
    const int lc = tid & 15;   // 0..15  (k within chunk)

    float acc[4][4] = {};
    float nsum = 0.f;

    for (int kk = 0; kk < C_; kk += 16) {
        __syncthreads();
        #pragma unroll
        for (int q = 0; q < 4; ++q) {
            int row = lr + q * 16;       // 0..63
            int gi = i0 + row;
            xa[lc][row] = (gi < T_) ? sigmoidf_(Xb[(size_t)gi * C_ + kk + lc]) : 0.f;
            int gj = j0 + row;
            ya[lc][row] = (gj < T_) ? sigmoidf_(Yb[(size_t)gj * C_ + kk + lc]) : 0.f;
        }
        __syncthreads();
        if (tid < 64) {
            #pragma unroll
            for (int k = 0; k < 16; ++k) { float v = xa[k][tid]; nsum += v * v; }
        } else if (tid < 128) {
            #pragma unroll
            for (int k = 0; k < 16; ++k) { float v = ya[k][tid - 64]; nsum += v * v; }
        }
        #pragma unroll
        for (int k = 0; k < 16; ++k) {
            float4 av = *(const float4*)&xa[k][ty * 4];
            float4 bv = *(const float4*)&ya[k][tx * 4];
            acc[0][0] += av.x * bv.x; acc[0][1] += av.x * bv.y; acc[0][2] += av.x * bv.z; acc[0][3] += av.x * bv.w;
            acc[1][0] += av.y * bv.x; acc[1][1] += av.y * bv.y; acc[1][2] += av.y * bv.z; acc[1][3] += av.y * bv.w;
            acc[2][0] += av.z * bv.x; acc[2][1] += av.z * bv.y; acc[2][2] += av.z * bv.z; acc[2][3] += av.z * bv.w;
            acc[3][0] += av.w * bv.x; acc[3][1] += av.w * bv.y; acc[3][2] += av.w * bv.z; acc[3][3] += av.w * bv.w;
        }
    }
    if (tid < 64) x2s[tid] = nsum;
    else if (tid < 128) y2s[tid - 64] = nsum;
    __syncthreads();

    float xs2[4], ys2[4];
    #pragma unroll
    for (int r = 0; r < 4; ++r) xs2[r] = x2s[ty * 4 + r];
    #pragma unroll
    for (int c = 0; c < 4; ++c) ys2[c] = y2s[tx * 4 + c];
    __syncthreads();

    float* Zt = smem;                     // [71][65]
    const int sb = ty >> 1;
    #pragma unroll
    for (int r = 0; r < 4; ++r)
        #pragma unroll
        for (int c = 0; c < 4; ++c)
            Zt[(4 * tx + c + sb) * 65 + (4 * ty + r)] = xs2[r] + ys2[c] - 2.f * acc[r][c] + WARP_V;
    __syncthreads();

    const int w0 = tid >> 6;              // wave id 0..3
    const int lane = tid & 63;
    const int iGlob = i0 + lane;
    const int sbl = lane >> 3;            // s(i) - 8ti
    const bool iok = iGlob < T_;
    const size_t ub = (size_t)(j0 + 8 * ti) * 800 + iGlob;
    #pragma unroll
    for (int it = 0; it < 18; ++it) {
        int w = w0 + it * 4;
        if (w > 70) break;
        int jrel = w - sbl;
        if (iok && (unsigned)jrel < 64u && (j0 + jrel) < T_)
            Dm[(size_t)kb * SLAB_ + ub + (size_t)w * 800] = Zt[w * 65 + lane];
    }
}

// ---------------------------------------------------------------- single-wave hard-min DTW, full inline asm
// R19 DW-form: workspace stores D' = D + W. Per cell:
//   m = min3(s_diag, m_up, m_left) + D'   (chain: min3 -> add, 2 deps/cell)
//   s = m - W                              (subrev, OFF the chain)
// vs R18's 3-dep chain (min3 -> +D -> +W). With 6-inst pair emission the
// chain-dependent edges are 3 insts = 6cy apart -> no stalls at dep-latency 6
// (R5/R6 timing fit L~6: 289 = 48x6 consecutive; pairing at 4cy still stalled).
// Register map:
//   v42 = BIG  v43,v44 = temps
//   v45 = tinSE (raw diag for STEP_E)  v46 = tinME (m for STEP_O's up)
//   v47 = tinSO (raw diag for STEP_O)  v48 = tinMO (m for STEP_E's up)
//   sE = v50-65  mE = v66-81  sO = v82-97  mO = v98-113
//   ring: 8 slots x 16 floats = v114-v241, 32 loads in flight, wait vmcnt(28)

#define DCELL2(aM,aD,aU,aL,aQ,aS, bM,bD,bU,bL,bQ,bS) \
  "v_min3_f32 v" #aM ", v" #aD ", v" #aU ", v" #aL "\n\t" \
  "v_min3_f32 v" #bM ", v" #bD ", v" #bU ", v" #bL "\n\t" \
  "v_add_f32 v" #aM ", v" #aM ", v" #aQ "\n\t" \
  "v_add_f32 v" #bM ", v" #bM ", v" #bQ "\n\t" \
  "v_subrev_f32 v" #aS ", %[wK], v" #aM "\n\t" \
  "v_subrev_f32 v" #bS ", %[wK], v" #bM "\n\t"

// STEP_E: reads sE/mE + tinSE/tinMO, writes sO/mO.
#define STEP_E(q0,q1,q2,q3,q4,q5,q6,q7,q8,q9,q10,q11,q12,q13,q14,q15) \
  DCELL2(98, 45, 48, 66, q0, 82,    106, 89, 73, 74, q8, 90) \
  DCELL2(99, 50, 98, 67, q1, 83,    107, 58, 106, 75, q9, 91) \
  DCELL2(100, 51, 99, 68, q2, 84,   108, 59, 107, 76, q10, 92) \
  DCELL2(101, 52, 100, 69, q3, 85,  109, 60, 108, 77, q11, 93) \
  DCELL2(102, 53, 101, 70, q4, 86,  110, 61, 109, 78, q12, 94) \
  DCELL2(103, 54, 102, 71, q5, 87,  111, 62, 110, 79, q13, 95) \
  DCELL2(104, 55, 103, 72, q6, 88,  112, 63, 111, 80, q14, 96) \
  DCELL2(105, 56, 104, 73, q7, 89,  113, 64, 112, 81, q15, 97)

// STEP_O: reads sO/mO + tinSO/tinME, writes sE/mE.
#define STEP_O(q0,q1,q2,q3,q4,q5,q6,q7,q8,q9,q10,q11,q12,q13,q14,q15) \
  DCELL2(66, 47, 46, 98, q0, 50,    74, 57, 105, 106, q8, 58) \
  DCELL2(67, 82, 66, 99, q1, 51,    75, 90, 74, 107, q9, 59) \
  DCELL2(68, 83, 67, 100, q2, 52,   76, 91, 75, 108, q10, 60) \
  DCELL2(69, 84, 68, 101, q3, 53,   77, 92, 76, 109, q11, 61) \
  DCELL2(70, 85, 69, 102, q4, 54,   78, 93, 77, 110, q12, 62) \
  DCELL2(71, 86, 70, 103, q5, 55,   79, 94, 78, 111, q13, 63) \
  DCELL2(72, 87, 71, 104, q6, 56,   80, 95, 79, 112, q14, 64) \
  DCELL2(73, 88, 72, 105, q7, 57,   81, 96, 80, 113, q15, 65)

// Handoff E: m15 = v113 (just written). tinME = shift(m15) (lane0->BIG);
// tinSE = tinME - W (off-chain; lane0: BIG-W still huge).
#define HO_E \
  "s_nop 1\n\t" \
  "v_mov_b32_dpp v43, v113 wave_shr:1 row_mask:0xf bank_mask:0xf bound_ctrl:0\n\t" \
  "v_cndmask_b32 v46, v43, v42, %[msk]\n\t" \
  "v_subrev_f32 v45, %[wK], v46\n\t"

#define HO_O \
  "s_nop 1\n\t" \
  "v_mov_b32_dpp v43, v81 wave_shr:1 row_mask:0xf bank_mask:0xf bound_ctrl:0\n\t" \
  "v_cndmask_b32 v48, v43, v42, %[msk]\n\t" \
  "v_subrev_f32 v47, %[wK], v48\n\t"

#define PREF(r0,r1,r2,r3,K) \
  "s_add_u32 %[st], %[su], " #K "\n\t" \
  "v_med3_i32 v43, %[st], %[vlo], %[vhi]\n\t" \
  "v_mad_u32_u24 v44, v43, %[c32], %[vl4]\n\t" \
  "global_load_dwordx4 " r0 ", v44, %[bp]\n\t" \
  "global_load_dwordx4 " r1 ", v44, %[bp] offset:16\n\t" \
  "global_load_dwordx4 " r2 ", v44, %[bp] offset:32\n\t" \
  "global_load_dwordx4 " r3 ", v44, %[bp] offset:48\n\t"

#define PREF0(K) PREF("v[114:117]","v[118:121]","v[122:125]","v[126:129]",K)
#define PREF1(K) PREF("v[130:133]","v[134:137]","v[138:141]","v[142:145]",K)
#define PREF2(K) PREF("v[146:149]","v[150:153]","v[154:157]","v[158:161]",K)
#define PREF3(K) PREF("v[162:165]","v[166:169]","v[170:173]","v[174:177]",K)
#define PREF4(K) PREF("v[178:181]","v[182:185]","v[186:189]","v[190:193]",K)
#define PREF5(K) PREF("v[194:197]","v[198:201]","v[202:205]","v[206:209]",K)
#define PREF6(K) PREF("v[210:213]","v[214:217]","v[218:221]","v[222:225]",K)
#define PREF7(K) PREF("v[226:229]","v[230:233]","v[234:237]","v[238:241]",K)

#define SLOT0 (114,115,116,117,118,119,120,121,122,123,124,125,126,127,128,129)
#define SLOT1 (130,131,132,133,134,135,136,137,138,139,140,141,142,143,144,145)
#define SLOT2 (146,147,148,149,150,151,152,153,154,155,156,157,158,159,160,161)
#define SLOT3 (162,163,164,165,166,167,168,169,170,171,172,173,174,175,176,177)
#define SLOT4 (178,179,180,181,182,183,184,185,186,187,188,189,190,191,192,193)
#define SLOT5 (194,195,196,197,198,199,200,201,202,203,204,205,206,207,208,209)
#define SLOT6 (210,211,212,213,214,215,216,217,218,219,220,221,222,223,224,225)
#define SLOT7 (226,227,228,229,230,231,232,233,234,235,236,237,238,239,240,241)

// Indirection so `M` is rescanned adjacent to the prescan-expanded paren list.
#define DTW_CALL(M, A) M A

#define MV(n) "v_mov_b32 v" #n ", v42\n\t"
#define W28 "s_waitcnt vmcnt(28)\n\t"

__global__ __launch_bounds__(64)
void dtw_wave_kernel(const float* __restrict__ Dm, float* __restrict__ dtwv) {
    const int kb = blockIdx.x;
    const int l  = threadIdx.x;
    const int lc = l < 49 ? l : 49;             // lanes 50-63 mirror lane 49
    const float* __restrict__ Dd = Dm + (size_t)kb * SLAB_;

    const int ti_l = lc >> 2;
    const int Jlo = ti_l >= 2 ? 64 * (ti_l - 2) : 0;
    const int Jhi = min(799, 64 * ti_l + 191);
    const int lo_u = (Jlo == 0) ? (2 * lc) : (Jlo + 2 * lc + 1);
    const int hi_u = Jhi + 2 * lc + 1;
    const unsigned lofs4 = (unsigned)(lc << 6);     // byte offset within u-row

    float res;
    unsigned su_d, st_d;

    asm volatile(
        // ---- init constants & state
        "v_mov_b32 v42, %[vbig]\n\t"
        MV(50) MV(51) MV(52) MV(53) MV(54) MV(55) MV(56) MV(57)
        MV(58) MV(59) MV(60) MV(61) MV(62) MV(63) MV(64) MV(65)
        MV(66) MV(67) MV(68) MV(69) MV(70) MV(71) MV(72) MV(73)
        MV(74) MV(75) MV(76) MV(77) MV(78) MV(79) MV(80) MV(81)
        MV(82) MV(83) MV(84) MV(85) MV(86) MV(87) MV(88) MV(89)
        MV(90) MV(91) MV(92) MV(93) MV(94) MV(95) MV(96) MV(97)
        MV(98) MV(99) MV(100) MV(101) MV(102) MV(103) MV(104) MV(105)
        MV(106) MV(107) MV(108) MV(109) MV(110) MV(111) MV(112) MV(113)
        "v_cndmask_b32 v45, v42, 0, %[msk]\n\t"   // tinSE: lane0 -> 0, else BIG
        "v_mov_b32 v46, v42\n\t"                  // tinME
        "v_mov_b32 v47, v42\n\t"                  // tinSO
        "v_mov_b32 v48, v42\n\t"                  // tinMO (read at step 0: BIG)
        "s_mov_b32 %[su], 0\n\t"
        // ---- prefill 8 slots (u = 0..7), 32 loads in flight
        PREF0(0) PREF1(1) PREF2(2) PREF3(3) PREF4(4) PREF5(5) PREF6(6) PREF7(7)
        // ---- main loop: 111 iters x 8 steps = steps 0..887
        "1:\n\t"
        W28 DTW_CALL(STEP_E, SLOT0) HO_E PREF0(8)
        W28 DTW_CALL(STEP_O, SLOT1) HO_O PREF1(9)
        W28 DTW_CALL(STEP_E, SLOT2) HO_E PREF2(10)
        W28 DTW_CALL(STEP_O, SLOT3) HO_O PREF3(11)
        W28 DTW_CALL(STEP_E, SLOT4) HO_E PREF4(12)
        W28 DTW_CALL(STEP_O, SLOT5) HO_O PREF5(13)
        W28 DTW_CALL(STEP_E, SLOT6) HO_E PREF6(14)
        W28 DTW_CALL(STEP_O, SLOT7) HO_O PREF7(15)
        "s_add_u32 %[su], %[su], 8\n\t"
        "s_cmp_lg_u32 %[su], 888\n\t"
        "s_cbranch_scc1 1b\n\t"
        // ---- tail: steps 888..898 (su = 888)
        W28 DTW_CALL(STEP_E, SLOT0) HO_E PREF0(8)            // 888, refill 896
        W28 DTW_CALL(STEP_O, SLOT1) HO_O PREF1(9)            // 889, refill 897
        W28 DTW_CALL(STEP_E, SLOT2) HO_E PREF2(10)           // 890, refill 898
        W28 DTW_CALL(STEP_O, SLOT3) HO_O                     // 891
        "s_waitcnt vmcnt(24)\n\t" DTW_CALL(STEP_E, SLOT4) HO_E   // 892
        "s_waitcnt vmcnt(20)\n\t" DTW_CALL(STEP_O, SLOT5) HO_O   // 893
        "s_waitcnt vmcnt(16)\n\t" DTW_CALL(STEP_E, SLOT6) HO_E   // 894
        "s_waitcnt vmcnt(12)\n\t" DTW_CALL(STEP_O, SLOT7) HO_O   // 895
        "s_waitcnt vmcnt(8)\n\t"  DTW_CALL(STEP_E, SLOT0) HO_E   // 896
        "s_waitcnt vmcnt(4)\n\t"  DTW_CALL(STEP_O, SLOT1) HO_O   // 897
        "s_waitcnt vmcnt(0)\n\t"  DTW_CALL(STEP_E, SLOT2)        // 898
        "v_mov_b32 %[res], v97\n\t"                              // raw s15 (lane 49)
        : [res] "=v"(res), [su] "=&s"(su_d), [st] "=&s"(st_d)
        : [vlo] "v"(lo_u), [vhi] "v"(hi_u), [vl4] "v"(lofs4),
          [vbig] "v"(BIGV), [wK] "s"(WARP_V), [c32] "s"(3200u),
          [msk] "s"(1ull), [bp] "s"((const void*)Dd)
        : "memory", "scc",
          "v42","v43","v44","v45","v46","v47","v48","v49",
          "v50","v51","v52","v53","v54","v55","v56","v57","v58","v59",
          "v60","v61","v62","v63","v64","v65","v66","v67","v68","v69",
          "v70","v71","v72","v73","v74","v75","v76","v77","v78","v79",
          "v80","v81","v82","v83","v84","v85","v86","v87","v88","v89",
          "v90","v91","v92","v93","v94","v95","v96","v97","v98","v99",
          "v100","v101","v102","v103","v104","v105","v106","v107","v108","v109",
          "v110","v111","v112","v113","v114","v115","v116","v117","v118","v119",
          "v120","v121","v122","v123","v124","v125","v126","v127","v128","v129",
          "v130","v131","v132","v133","v134","v135","v136","v137","v138","v139",
          "v140","v141","v142","v143","v144","v145","v146","v147","v148","v149",
          "v150","v151","v152","v153","v154","v155","v156","v157","v158","v159",
          "v160","v161","v162","v163","v164","v165","v166","v167","v168","v169",
          "v170","v171","v172","v173","v174","v175","v176","v177","v178","v179",
          "v180","v181","v182","v183","v184","v185","v186","v187","v188","v189",
          "v190","v191","v192","v193","v194","v195","v196","v197","v198","v199",
          "v200","v201","v202","v203","v204","v205","v206","v207","v208","v209",
          "v210","v211","v212","v213","v214","v215","v216","v217","v218","v219",
          "v220","v221","v222","v223","v224","v225","v226","v227","v228","v229",
          "v230","v231","v232","v233","v234","v235","v236","v237","v238","v239",
          "v240","v241"
    );

    if (l == 49) dtwv[kb] = res;
}

// ---------------------------------------------------------------- finalize (scalars)
__global__ void finalize_kernel(const float* __restrict__ dtwv, const int* __restrict__ mel_lens,
                                const int* __restrict__ src_lens, const float* __restrict__ durations,
                                const float* __restrict__ mus, const float* __restrict__ log_vars,
                                const int* __restrict__ step, float* __restrict__ out) {
    const int lane = threadIdx.x;  // 64 threads, one wave

    float v = (lane < KB_) ? dtwv[lane] : 0.f;
    for (int o = 32; o; o >>= 1) v += __shfl_down(v, o);

    float w = (lane < B_) ? 1.f / (K_ * (float)mel_lens[lane]) : 0.f;
    for (int o = 32; o; o >>= 1) w += __shfl_down(w, o);

    float du = 0.f;
    if (lane < B_) {
        float s = 0.f;
        for (int j = 0; j < S_; ++j) s += durations[lane * S_ + j];
        du = fabsf(s - (float)mel_lens[lane]) / (float)src_lens[lane];
    }
    for (int o = 32; o; o >>= 1) du += __shfl_down(du, o);

    float kl = 0.f;
    for (int j = lane; j < B_ * Z_; j += 64) {
        float muv = mus[j], lv = log_vars[j];
        kl += 1.f + lv - muv * muv - expf(lv);
    }
    for (int o = 32; o; o >>= 1) kl += __shfl_down(kl, o);

    if (lane == 0) {
        float mel_iter_loss = v / (float)B_;
        float mel_loss = mel_iter_loss * (w / (float)B_);
        float dur_loss = 2.0f * du / (float)B_;
        float kl_loss = -0.5f * kl;
        int st = step[0];
        float beta = (st < 2000) ? 0.f : ((st >= 8000) ? 1.f : (float)(st - 2000) / 6000.f);
        out[0] = mel_loss + dur_loss + beta * kl_loss;
        out[1] = mel_loss;
        out[2] = dur_loss;
        out[3] = kl_loss;
        out[4] = beta;
    }
}

// ---------------------------------------------------------------- launch
extern "C" void kernel_launch(void* const* d_in, const int* in_sizes, int n_in,
                              void* d_out, int out_size, void* d_ws, size_t ws_size,
                              hipStream_t stream) {
    const float* mel_iters   = (const float*)d_in[0];
    const float* mel_targets = (const float*)d_in[1];
    const int*   mel_lens    = (const int*)d_in[2];
    const int*   src_lens    = (const int*)d_in[3];
    const float* durations   = (const float*)d_in[4];
    const float* mus         = (const float*)d_in[5];
    const float* log_vars    = (const float*)d_in[6];
    const int*   step        = (const int*)d_in[7];
    float* out = (float*)d_out;

    float* ws   = (float*)d_ws;
    float* Dm   = ws;                              // 32 * 720,000 floats = 92.16 MB
    float* dtwv = Dm + (size_t)KB_ * SLAB_;        //        32

    fill_edge<<<KB_, 192, 0, stream>>>(Dm);

    gemm_band<<<dim3(5, 13, KB_), 256, 0, stream>>>(mel_iters, mel_targets, Dm);

    dtw_wave_kernel<<<KB_, 64, 0, stream>>>(Dm, dtwv);

    finalize_kernel<<<1, 64, 0, stream>>>(dtwv, mel_lens, src_lens, durations, mus, log_vars, step, out);
}

// Round 8
// 213.717 us; speedup vs baseline: 1.2480x; 1.0115x over previous
//
#include <hip/hip_runtime.h>
#include <math.h>
#include <stdint.h>

// Problem constants (fixed by setup_inputs)
constexpr int K_ = 4, B_ = 8, T_ = 800, C_ = 80, S_ = 128, Z_ = 32;
constexpr int KB_ = K_ * B_;        // 32
constexpr int TC_ = T_ * C_;        // 64000

#define BIGV   1e8f
#define WARP_V 256.0f

// R12 sheared-stream layout (g=8): Q[u][i] = D[i][u - (i>>3)].
// Lane l owns rows 16l..16l+15 = groups m=0 (cols j0 = u-2l) and m=1 (j1 = j0-1).
constexpr int NU_   = 900;            // u = j + (i>>3) <= 799 + 99 = 898
constexpr int SLAB_ = NU_ * 800;      // 720,000 floats per problem (92.16 MB total)

__device__ __forceinline__ float sigmoidf_(float v) {
    return 1.f / (1.f + __expf(-v));
}

// ---------------------------------------------------------------- fill j = -1 ghost cells with BIG
__global__ void fill_edge(float* __restrict__ Dm) {
    int kb = blockIdx.x;
    int t = threadIdx.x;
    if (t < 184) {
        int i = 8 + t;     // i in [8, 191]
        Dm[(size_t)kb * SLAB_ + (size_t)((i >> 3) - 1) * 800 + i] = BIGV;
    }
}

// ---------------------------------------------------------------- banded GEMM -> sheared Q (norms fused)
// R20 rewrite: single-stage the full 64x80 tiles (float4 global loads, sigmoid
// once), ONE norm pass (k-ascending, same summation order as before), one
// 80-deep FMA loop, 2 barriers instead of 12. Epilogue unchanged (raw D).
__global__ __launch_bounds__(256) void gemm_band(const float* __restrict__ mel_iters,
                                                 const float* __restrict__ mel_targets,
                                                 float* __restrict__ Dm) {
    const int kb = blockIdx.z;
    const int b  = kb & 7;
    const int ti = blockIdx.y;
    const int tj = ti + (int)blockIdx.x - 2;
    if ((unsigned)tj > 12u) return;

    const float* __restrict__ Xb = mel_iters + (size_t)kb * TC_;
    const float* __restrict__ Yb = mel_targets + (size_t)b * TC_;

    __shared__ float smem[10880];            // xa[80][68] | ya[80][68]; phase2: Zt[71][65]
    __shared__ float x2s[64], y2s[64];
    float (*xa)[68] = (float(*)[68])smem;
    float (*ya)[68] = (float(*)[68])(smem + 5440);

    const int tid = threadIdx.x;
    const int tx = tid & 15, ty = tid >> 4;
    const int i0 = ti * 64, j0 = tj * 64;

    // ---- single-stage: sigmoid(X) 64x80 and sigmoid(Y) 64x80 into LDS
    {
        const int row = tid & 63, seg = tid >> 6;      // 4 threads per row
        const int gi = min(i0 + row, T_ - 1);          // clamp: OOB rows never stored
        const int gj = min(j0 + row, T_ - 1);
        const float4* Xr = (const float4*)(Xb + (size_t)gi * C_);
        const float4* Yr = (const float4*)(Yb + (size_t)gj * C_);
        #pragma unroll
        for (int m = 0; m < 5; ++m) {
            const int k4 = seg * 5 + m;                // float4 index 0..19
            float4 xv = Xr[k4], yv = Yr[k4];
            const int k = k4 * 4;
            xa[k + 0][row] = sigmoidf_(xv.x); xa[k + 1][row] = sigmoidf_(xv.y);
            xa[k + 2][row] = sigmoidf_(xv.z); xa[k + 3][row] = sigmoidf_(xv.w);
            ya[k + 0][row] = sigmoidf_(yv.x); ya[k + 1][row] = sigmoidf_(yv.y);
            ya[k + 2][row] = sigmoidf_(yv.z); ya[k + 3][row] = sigmoidf_(yv.w);
        }
    }
    __syncthreads();

    // ---- row norms, k ascending (same order as the old per-chunk sum)
    if (tid < 64) {
        float s = 0.f;
        for (int k = 0; k < C_; ++k) { float v = xa[k][tid]; s += v * v; }
        x2s[tid] = s;
    } else if (tid < 128) {
        float s = 0.f;
        for (int k = 0; k < C_; ++k) { float v = ya[k][tid - 64]; s += v * v; }
        y2s[tid - 64] = s;
    }

    // ---- 80-deep FMA (k ascending, same accumulation order as before)
    float acc[4][4] = {};
    #pragma unroll 16
    for (int k = 0; k < C_; ++k) {
        float4 av = *(const float4*)&xa[k][ty * 4];
        float4 bv = *(const float4*)&ya[k][tx * 4];
        acc[0][0] += av.x * bv.x; acc[0][1] += av.x * bv.y; acc[0][2] += av.x * bv.z; acc[0][3] += av.x * bv.w;
        acc[1][0] += av.y * bv.x; acc[1][1] += av.y * bv.y; acc[1][2] += av.y * bv.z; acc[1][3] += av.y * bv.w;
        acc[2][0] += av.z * bv.x; acc[2][1] += av.z * bv.y; acc[2][2] += av.z * bv.z; acc[2][3] += av.z * bv.w;
        acc[3][0] += av.w * bv.x; acc[3][1] += av.w * bv.y; acc[3][2] += av.w * bv.z; acc[3][3] += av.w * bv.w;
    }
    __syncthreads();     // xa/ya dead from here; x2s/y2s valid for everyone

    float xs2[4], ys2[4];
    #pragma unroll
    for (int r = 0; r < 4; ++r) xs2[r] = x2s[ty * 4 + r];
    #pragma unroll
    for (int c = 0; c < 4; ++c) ys2[c] = y2s[tx * 4 + c];

    // stage into sheared LDS tile: Zt[u_rel][iLoc], u_rel = 4tx + c + (ty>>1)
    float* Zt = smem;                     // [71][65] (aliases xa region, post-barrier)
    const int sb = ty >> 1;
    #pragma unroll
    for (int r = 0; r < 4; ++r)
        #pragma unroll
        for (int c = 0; c < 4; ++c)
            Zt[(4 * tx + c + sb) * 65 + (4 * ty + r)] = xs2[r] + ys2[c] - 2.f * acc[r][c];
    __syncthreads();

    // coalesced u-row stores: u_global = j0 + 8ti + w, 64 contiguous floats at i0
    const int w0 = tid >> 6;              // wave id 0..3
    const int lane = tid & 63;
    const int iGlob = i0 + lane;
    const int sbl = lane >> 3;            // s(i) - 8ti
    const bool iok = iGlob < T_;
    const size_t ub = (size_t)(j0 + 8 * ti) * 800 + iGlob;
    #pragma unroll
    for (int it = 0; it < 18; ++it) {
        int w = w0 + it * 4;
        if (w > 70) break;
        int jrel = w - sbl;
        if (iok && (unsigned)jrel < 64u && (j0 + jrel) < T_)
            Dm[(size_t)kb * SLAB_ + ub + (size_t)w * 800] = Zt[w * 65 + lane];
    }
}

// ---------------------------------------------------------------- single-wave hard-min DTW, full inline asm
// R20 = exact R18 (best measured: 99.4us, absmax 0). Dual-chain 6-inst pair
// interleave; raw-D workspace. Register map:
//   v42 = BIG  v43,v44 = temps  v45 = tinE  v46 = tinWE  v47 = tinO  v48 = tinWO
//   sE = v50-65  wE = v66-81  sO = v82-97  wO = v98-113
//   ring: 8 slots x 16 floats = v114-v241, 32 loads in flight, wait vmcnt(28)

#define DCELL2(aS,aA,aB,aC,aD,aW, bS,bA,bB,bC,bD,bW) \
  "v_min3_f32 v" #aS ", v" #aA ", v" #aB ", v" #aC "\n\t" \
  "v_min3_f32 v" #bS ", v" #bA ", v" #bB ", v" #bC "\n\t" \
  "v_add_f32 v" #aS ", v" #aS ", v" #aD "\n\t" \
  "v_add_f32 v" #bS ", v" #bS ", v" #bD "\n\t" \
  "v_add_f32 v" #aW ", %[wK], v" #aS "\n\t" \
  "v_add_f32 v" #bW ", %[wK], v" #bS "\n\t"

#define STEP_E(q0,q1,q2,q3,q4,q5,q6,q7,q8,q9,q10,q11,q12,q13,q14,q15) \
  DCELL2(82, 45, 48, 66, q0, 98,    90, 89, 73, 74, q8, 106) \
  DCELL2(83, 50, 98, 67, q1, 99,    91, 58, 106, 75, q9, 107) \
  DCELL2(84, 51, 99, 68, q2, 100,   92, 59, 107, 76, q10, 108) \
  DCELL2(85, 52, 100, 69, q3, 101,  93, 60, 108, 77, q11, 109) \
  DCELL2(86, 53, 101, 70, q4, 102,  94, 61, 109, 78, q12, 110) \
  DCELL2(87, 54, 102, 71, q5, 103,  95, 62, 110, 79, q13, 111) \
  DCELL2(88, 55, 103, 72, q6, 104,  96, 63, 111, 80, q14, 112) \
  DCELL2(89, 56, 104, 73, q7, 105,  97, 64, 112, 81, q15, 113)

#define STEP_O(q0,q1,q2,q3,q4,q5,q6,q7,q8,q9,q10,q11,q12,q13,q14,q15) \
  DCELL2(50, 47, 46, 98, q0, 66,    58, 57, 105, 106, q8, 74) \
  DCELL2(51, 82, 66, 99, q1, 67,    59, 90, 74, 107, q9, 75) \
  DCELL2(52, 83, 67, 100, q2, 68,   60, 91, 75, 108, q10, 76) \
  DCELL2(53, 84, 68, 101, q3, 69,   61, 92, 76, 109, q11, 77) \
  DCELL2(54, 85, 69, 102, q4, 70,   62, 93, 77, 110, q12, 78) \
  DCELL2(55, 86, 70, 103, q5, 71,   63, 94, 78, 111, q13, 79) \
  DCELL2(56, 87, 71, 104, q6, 72,   64, 95, 79, 112, q14, 80) \
  DCELL2(57, 88, 72, 105, q7, 73,   65, 96, 80, 113, q15, 81)

#define HO_E \
  "s_nop 1\n\t" \
  "v_mov_b32_dpp v43, v97 wave_shr:1 row_mask:0xf bank_mask:0xf bound_ctrl:0\n\t" \
  "v_cndmask_b32 v45, v43, v42, %[msk]\n\t" \
  "v_add_f32 v46, %[wK], v45\n\t"

#define HO_O \
  "s_nop 1\n\t" \
  "v_mov_b32_dpp v43, v65 wave_shr:1 row_mask:0xf bank_mask:0xf bound_ctrl:0\n\t" \
  "v_cndmask_b32 v47, v43, v42, %[msk]\n\t" \
  "v_add_f32 v48, %[wK], v47\n\t"

#define PREF(r0,r1,r2,r3,K) \
  "s_add_u32 %[st], %[su], " #K "\n\t" \
  "v_med3_i32 v43, %[st], %[vlo], %[vhi]\n\t" \
  "v_mad_u32_u24 v44, v43, %[c32], %[vl4]\n\t" \
  "global_load_dwordx4 " r0 ", v44, %[bp]\n\t" \
  "global_load_dwordx4 " r1 ", v44, %[bp] offset:16\n\t" \
  "global_load_dwordx4 " r2 ", v44, %[bp] offset:32\n\t" \
  "global_load_dwordx4 " r3 ", v44, %[bp] offset:48\n\t"

#define PREF0(K) PREF("v[114:117]","v[118:121]","v[122:125]","v[126:129]",K)
#define PREF1(K) PREF("v[130:133]","v[134:137]","v[138:141]","v[142:145]",K)
#define PREF2(K) PREF("v[146:149]","v[150:153]","v[154:157]","v[158:161]",K)
#define PREF3(K) PREF("v[162:165]","v[166:169]","v[170:173]","v[174:177]",K)
#define PREF4(K) PREF("v[178:181]","v[182:185]","v[186:189]","v[190:193]",K)
#define PREF5(K) PREF("v[194:197]","v[198:201]","v[202:205]","v[206:209]",K)
#define PREF6(K) PREF("v[210:213]","v[214:217]","v[218:221]","v[222:225]",K)
#define PREF7(K) PREF("v[226:229]","v[230:233]","v[234:237]","v[238:241]",K)

#define SLOT0 (114,115,116,117,118,119,120,121,122,123,124,125,126,127,128,129)
#define SLOT1 (130,131,132,133,134,135,136,137,138,139,140,141,142,143,144,145)
#define SLOT2 (146,147,148,149,150,151,152,153,154,155,156,157,158,159,160,161)
#define SLOT3 (162,163,164,165,166,167,168,169,170,171,172,173,174,175,176,177)
#define SLOT4 (178,179,180,181,182,183,184,185,186,187,188,189,190,191,192,193)
#define SLOT5 (194,195,196,197,198,199,200,201,202,203,204,205,206,207,208,209)
#define SLOT6 (210,211,212,213,214,215,216,217,218,219,220,221,222,223,224,225)
#define SLOT7 (226,227,228,229,230,231,232,233,234,235,236,237,238,239,240,241)

// Indirection so `M` is rescanned adjacent to the prescan-expanded paren list.
#define DTW_CALL(M, A) M A

#define MV(n) "v_mov_b32 v" #n ", v42\n\t"
#define W28 "s_waitcnt vmcnt(28)\n\t"

__global__ __launch_bounds__(64)
void dtw_wave_kernel(const float* __restrict__ Dm, float* __restrict__ dtwv) {
    const int kb = blockIdx.x;
    const int l  = threadIdx.x;
    const int lc = l < 49 ? l : 49;             // lanes 50-63 mirror lane 49
    const float* __restrict__ Dd = Dm + (size_t)kb * SLAB_;

    const int ti_l = lc >> 2;
    const int Jlo = ti_l >= 2 ? 64 * (ti_l - 2) : 0;
    const int Jhi = min(799, 64 * ti_l + 191);
    const int lo_u = (Jlo == 0) ? (2 * lc) : (Jlo + 2 * lc + 1);
    const int hi_u = Jhi + 2 * lc + 1;
    const unsigned lofs4 = (unsigned)(lc << 6);     // byte offset within u-row

    float res;
    unsigned su_d, st_d;

    asm volatile(
        // ---- init constants & state
        "v_mov_b32 v42, %[vbig]\n\t"
        MV(50) MV(51) MV(52) MV(53) MV(54) MV(55) MV(56) MV(57)
        MV(58) MV(59) MV(60) MV(61) MV(62) MV(63) MV(64) MV(65)
        MV(66) MV(67) MV(68) MV(69) MV(70) MV(71) MV(72) MV(73)
        MV(74) MV(75) MV(76) MV(77) MV(78) MV(79) MV(80) MV(81)
        MV(82) MV(83) MV(84) MV(85) MV(86) MV(87) MV(88) MV(89)
        MV(90) MV(91) MV(92) MV(93) MV(94) MV(95) MV(96) MV(97)
        MV(98) MV(99) MV(100) MV(101) MV(102) MV(103) MV(104) MV(105)
        MV(106) MV(107) MV(108) MV(109) MV(110) MV(111) MV(112) MV(113)
        "v_cndmask_b32 v45, v42, 0, %[msk]\n\t"   // tinE: lane0 -> 0, else BIG
        "v_mov_b32 v46, v42\n\t"                  // tinWE (never read before write)
        "v_mov_b32 v47, v42\n\t"                  // tinO
        "v_mov_b32 v48, v42\n\t"                  // tinWO (read at step 0: BIG)
        "s_mov_b32 %[su], 0\n\t"
        // ---- prefill 8 slots (u = 0..7), 32 loads in flight
        PREF0(0) PREF1(1) PREF2(2) PREF3(3) PREF4(4) PREF5(5) PREF6(6) PREF7(7)
        // ---- main loop: 111 iters x 8 steps = steps 0..887
        "1:\n\t"
        W28 DTW_CALL(STEP_E, SLOT0) HO_E PREF0(8)
        W28 DTW_CALL(STEP_O, SLOT1) HO_O PREF1(9)
        W28 DTW_CALL(STEP_E, SLOT2) HO_E PREF2(10)
        W28 DTW_CALL(STEP_O, SLOT3) HO_O PREF3(11)
        W28 DTW_CALL(STEP_E, SLOT4) HO_E PREF4(12)
        W28 DTW_CALL(STEP_O, SLOT5) HO_O PREF5(13)
        W28 DTW_CALL(STEP_E, SLOT6) HO_E PREF6(14)
        W28 DTW_CALL(STEP_O, SLOT7) HO_O PREF7(15)
        "s_add_u32 %[su], %[su], 8\n\t"
        "s_cmp_lg_u32 %[su], 888\n\t"
        "s_cbranch_scc1 1b\n\t"
        // ---- tail: steps 888..898 (su = 888)
        W28 DTW_CALL(STEP_E, SLOT0) HO_E PREF0(8)            // 888, refill 896
        W28 DTW_CALL(STEP_O, SLOT1) HO_O PREF1(9)            // 889, refill 897
        W28 DTW_CALL(STEP_E, SLOT2) HO_E PREF2(10)           // 890, refill 898
        W28 DTW_CALL(STEP_O, SLOT3) HO_O                     // 891
        "s_waitcnt vmcnt(24)\n\t" DTW_CALL(STEP_E, SLOT4) HO_E   // 892
        "s_waitcnt vmcnt(20)\n\t" DTW_CALL(STEP_O, SLOT5) HO_O   // 893
        "s_waitcnt vmcnt(16)\n\t" DTW_CALL(STEP_E, SLOT6) HO_E   // 894
        "s_waitcnt vmcnt(12)\n\t" DTW_CALL(STEP_O, SLOT7) HO_O   // 895
        "s_waitcnt vmcnt(8)\n\t"  DTW_CALL(STEP_E, SLOT0) HO_E   // 896
        "s_waitcnt vmcnt(4)\n\t"  DTW_CALL(STEP_O, SLOT1) HO_O   // 897
        "s_waitcnt vmcnt(0)\n\t"  DTW_CALL(STEP_E, SLOT2)        // 898
        "v_mov_b32 %[res], v97\n\t"
        : [res] "=v"(res), [su] "=&s"(su_d), [st] "=&s"(st_d)
        : [vlo] "v"(lo_u), [vhi] "v"(hi_u), [vl4] "v"(lofs4),
          [vbig] "v"(BIGV), [wK] "s"(WARP_V), [c32] "s"(3200u),
          [msk] "s"(1ull), [bp] "s"((const void*)Dd)
        : "memory", "scc",
          "v42","v43","v44","v45","v46","v47","v48","v49",
          "v50","v51","v52","v53","v54","v55","v56","v57","v58","v59",
          "v60","v61","v62","v63","v64","v65","v66","v67","v68","v69",
          "v70","v71","v72","v73","v74","v75","v76","v77","v78","v79",
          "v80","v81","v82","v83","v84","v85","v86","v87","v88","v89",
          "v90","v91","v92","v93","v94","v95","v96","v97","v98","v99",
          "v100","v101","v102","v103","v104","v105","v106","v107","v108","v109",
          "v110","v111","v112","v113","v114","v115","v116","v117","v118","v119",
          "v120","v121","v122","v123","v124","v125","v126","v127","v128","v129",
          "v130","v131","v132","v133","v134","v135","v136","v137","v138","v139",
          "v140","v141","v142","v143","v144","v145","v146","v147","v148","v149",
          "v150","v151","v152","v153","v154","v155","v156","v157","v158","v159",
          "v160","v161","v162","v163","v164","v165","v166","v167","v168","v169",
          "v170","v171","v172","v173","v174","v175","v176","v177","v178","v179",
          "v180","v181","v182","v183","v184","v185","v186","v187","v188","v189",
          "v190","v191","v192","v193","v194","v195","v196","v197","v198","v199",
          "v200","v201","v202","v203","v204","v205","v206","v207","v208","v209",
          "v210","v211","v212","v213","v214","v215","v216","v217","v218","v219",
          "v220","v221","v222","v223","v224","v225","v226","v227","v228","v229",
          "v230","v231","v232","v233","v234","v235","v236","v237","v238","v239",
          "v240","v241"
    );

    if (l == 49) dtwv[kb] = res;
}

// ---------------------------------------------------------------- finalize (scalars)
__global__ void finalize_kernel(const float* __restrict__ dtwv, const int* __restrict__ mel_lens,
                                const int* __restrict__ src_lens, const float* __restrict__ durations,
                                const float* __restrict__ mus, const float* __restrict__ log_vars,
                                const int* __restrict__ step, float* __restrict__ out) {
    const int lane = threadIdx.x;  // 64 threads, one wave

    float v = (lane < KB_) ? dtwv[lane] : 0.f;
    for (int o = 32; o; o >>= 1) v += __shfl_down(v, o);

    float w = (lane < B_) ? 1.f / (K_ * (float)mel_lens[lane]) : 0.f;
    for (int o = 32; o; o >>= 1) w += __shfl_down(w, o);

    float du = 0.f;
    if (lane < B_) {
        float s = 0.f;
        for (int j = 0; j < S_; ++j) s += durations[lane * S_ + j];
        du = fabsf(s - (float)mel_lens[lane]) / (float)src_lens[lane];
    }
    for (int o = 32; o; o >>= 1) du += __shfl_down(du, o);

    float kl = 0.f;
    for (int j = lane; j < B_ * Z_; j += 64) {
        float muv = mus[j], lv = log_vars[j];
        kl += 1.f + lv - muv * muv - expf(lv);
    }
    for (int o = 32; o; o >>= 1) kl += __shfl_down(kl, o);

    if (lane == 0) {
        float mel_iter_loss = v / (float)B_;
        float mel_loss = mel_iter_loss * (w / (float)B_);
        float dur_loss = 2.0f * du / (float)B_;
        float kl_loss = -0.5f * kl;
        int st = step[0];
        float beta = (st < 2000) ? 0.f : ((st >= 8000) ? 1.f : (float)(st - 2000) / 6000.f);
        out[0] = mel_loss + dur_loss + beta * kl_loss;
        out[1] = mel_loss;
        out[2] = dur_loss;
        out[3] = kl_loss;
        out[4] = beta;
    }
}

// ---------------------------------------------------------------- launch
extern "C" void kernel_launch(void* const* d_in, const int* in_sizes, int n_in,
                              void* d_out, int out_size, void* d_ws, size_t ws_size,
                              hipStream_t stream) {
    const float* mel_iters   = (const float*)d_in[0];
    const float* mel_targets = (const float*)d_in[1];
    const int*   mel_lens    = (const int*)d_in[2];
    const int*   src_lens    = (const int*)d_in[3];
    const float* durations   = (const float*)d_in[4];
    const float* mus         = (const float*)d_in[5];
    const float* log_vars    = (const float*)d_in[6];
    const int*   step        = (const int*)d_in[7];
    float* out = (float*)d_out;

    float* ws   = (float*)d_ws;
    float* Dm   = ws;                              // 32 * 720,000 floats = 92.16 MB
    float* dtwv = Dm + (size_t)KB_ * SLAB_;        //        32

    fill_edge<<<KB_, 192, 0, stream>>>(Dm);

    gemm_band<<<dim3(5, 13, KB_), 256, 0, stream>>>(mel_iters, mel_targets, Dm);

    dtw_wave_kernel<<<KB_, 64, 0, stream>>>(Dm, dtwv);

    finalize_kernel<<<1, 64, 0, stream>>>(dtwv, mel_lens, src_lens, durations, mus, log_vars, step, out);
}